// Round 10
// baseline (65.373 us; speedup 1.0000x reference)
//
#include <hip/hip_runtime.h>

// Dims fixed by reference setup_inputs
#define CIN  128
#define CHUNKF 32768       // HW*T floats per (n, channel)

typedef __attribute__((ext_vector_type(2))) float f32x2;

// ws float layout:
// [0,4096)      qw1   [32][128] f32  (kappa input)
// [4096,8192)   qw2   [128][32] f32  (kappa input)
// [8192,8320)   msum  [128]
// [8320,8448)   kappa [128]
// [8448,10496)  w1hT  ushort[128 c][32 o1]  bf16 (exact)
// [10496,12544) w2hT  ushort[32 j][128 o2]  bf16 (exact)

// blocks [0,2048): mean partial sums; blocks [2048,2208): weight-norm rows.
__global__ __launch_bounds__(256) void wnorm_mean_kernel(
    const float* __restrict__ x,
    const float* __restrict__ v1, const float* __restrict__ g1,
    const float* __restrict__ v2, const float* __restrict__ g2,
    float* __restrict__ ws) {
  int tid = threadIdx.x;
  if (blockIdx.x < 2048) {
    int b = blockIdx.x;
    int chunk = b >> 2, quarter = b & 3;      // chunk = n*128 + i
    int i = chunk & 127;
    const float4* xp = (const float4*)(x + (size_t)chunk * CHUNKF + (size_t)quarter * 8192);
    float acc = 0.f;
#pragma unroll
    for (int it = 0; it < 8; ++it) {
      int f4i = tid + 256 * it;
      float4 v = xp[f4i];
      int t0 = (4 * f4i) & 31;
      acc += v.x * (float)(32 - t0) + v.y * (float)(31 - t0)
           + v.z * (float)(30 - t0) + v.w * (float)(29 - t0);
    }
    for (int off = 32; off >= 1; off >>= 1) acc += __shfl_down(acc, off);
    __shared__ float part[4];
    if ((tid & 63) == 0) part[tid >> 6] = acc;
    __syncthreads();
    if (tid == 0) atomicAdd(&ws[8192 + i], part[0] + part[1] + part[2] + part[3]);
  } else {
    int b = blockIdx.x - 2048;
    bool first = (b < 32);
    int row = first ? b : b - 32;
    int len = first ? 128 : 32;
    const float* v = first ? v1 : v2;
    const float* g = first ? g1 : g2;

    double val = 0.0;
    if (tid < len) { double t = (double)v[row * len + tid]; val = t * t; }
    for (int off = 32; off >= 1; off >>= 1) val += __shfl_down(val, off);
    __shared__ double partial[4];
    if ((tid & 63) == 0) partial[tid >> 6] = val;
    __syncthreads();
    double norm = sqrt(partial[0] + partial[1]);
    if (tid < len) {
      double w = (double)g[row] * (double)v[row * len + tid] / norm;
      double qd = rint(w * 32.0) * 0.03125;        // step = 2/64, round-half-even
      qd = fmin(fmax(qd, -2.0), 1.984375);
      float qf = (float)qd;                        // exactly representable in bf16
      ushort bf = (ushort)(__float_as_uint(qf) >> 16);
      if (first) {                                 // row=o1, tid=c
        ws[row * 128 + tid] = qf;                              // qw1 f32
        ((ushort*)(ws + 8448))[tid * 32 + row] = bf;           // w1hT [c][o1]
      } else {                                     // row=o2, tid=j
        ws[4096 + row * 32 + tid] = qf;                        // qw2 f32
        ((ushort*)(ws + 10496))[tid * 128 + row] = bf;         // w2hT [j][o2]
      }
    }
  }
}

// kappa[o2] = sum_j qw2[o2][j] * (sum_c qw1[j][c] * mbar[c])
__global__ __launch_bounds__(128) void kappa_kernel(float* __restrict__ ws) {
  __shared__ float z[32];
  int tid = threadIdx.x;
  const float* qw1 = ws;
  const float* qw2 = ws + 4096;
  const float* msum = ws + 8192;
  if (tid < 32) {
    float acc = 0.f;
    for (int c = 0; c < 128; ++c) acc += qw1[tid * 128 + c] * msum[c];
    z[tid] = acc * (1.0f / 131072.0f);
  }
  __syncthreads();
  float k = 0.f;
  for (int j = 0; j < 32; ++j) k += qw2[tid * 32 + j] * z[j];
  ws[8320 + tid] = k;
}

// Fused: u = qw2*(qw1*x); S = cumsum_t u; a = clip(S - kappa); out = diff_t a.
// Block = 128 thr = 2 waves; wave owns 2 positions (block covers 4). Grid 1024.
// Stage 1: lane l = (p1:1)(oh:2)(u:3): pos = w*2+p1, o1 = oh*8+{0..7},
//   t = 4u..4u+3. Per c: 1 b128 x-read + 1 b128 w1-read(bf16x8) -> 16 pkFMA.
//   x staged in LDS double-buffer (barrier -> prefetch -> compute -> write-late).
// z -> LDS [pos][j][t] (one barrier; overlays x-stage region).
// Stage 2 per pos (sequential): lane = (oq:3)(u2:3): o2 = oq*16+{0..15},
//   t-quad. Per j: 1 b128 z + 2 b128 w2(bf16) -> 32 pkFMA. Epilogue = round-7.
__global__ __launch_bounds__(128, 2) void fused_kernel(
    const float* __restrict__ x, const float* __restrict__ ws,
    float* __restrict__ out) {
  const uint* w1t32 = (const uint*)(ws + 8448);    // 2048 u32
  const uint* w2t32 = (const uint*)(ws + 10496);   // 2048 u32
  const float* kap  = ws + 8320;

  __shared__ __align__(16) float smem[8192];       // 32 KB
  // [0,4096): x stage [2][16c][4pos][32t]  -> later z [4pos][32j][32t]
  // [4096,6144): w1hT bf16 (u32 view: c*16 + o1/2)
  // [6144,8192): w2hT bf16 (u32 view: j*64 + o2/2)
  uint* w1d = (uint*)(smem + 4096);
  uint* w2d = (uint*)(smem + 6144);

  const int tid = threadIdx.x;
  const int w   = tid >> 6;
  const int l   = tid & 63;
  const int p1  = l >> 5;            // stage-1 position within wave
  const int oh  = (l >> 3) & 3;      // stage-1 o1-group (8 outputs)
  const int u   = l & 7;             // t-quad: t = 4u..4u+3
  const int posw = w * 2 + p1;       // 0..3 (stage-1)
  const int oq  = l >> 3;            // stage-2 o2-group (16 outputs)
  const int u2  = l & 7;             // stage-2 t-quad

  const int nb  = blockIdx.x >> 8;
  const int hw0 = (blockIdx.x & 255) * 4;
  const float* xblk = x + (size_t)nb * CIN * CHUNKF + (size_t)hw0 * 32;
  // staging base: channel-within-chunk = k*4 + (tid>>5), row offset (tid&31)*4
  const float* xstage = xblk + (size_t)(tid >> 5) * CHUNKF + (tid & 31) * 4;

  // issue chunk-0 loads first (L3 latency hides under weight preload)
  float4 xr[4];
#pragma unroll
  for (int k = 0; k < 4; ++k)
    xr[k] = *(const float4*)(xstage + (size_t)(k * 4) * CHUNKF);

  // weight tables -> LDS: 2048 u32 each, 128 threads -> 16 iterations each
#pragma unroll
  for (int k = 0; k < 16; ++k) w1d[k * 128 + tid] = w1t32[k * 128 + tid];
#pragma unroll
  for (int k = 0; k < 16; ++k) w2d[k * 128 + tid] = w2t32[k * 128 + tid];

  // stage chunk 0 into buf 0
#pragma unroll
  for (int k = 0; k < 4; ++k)
    *(float4*)&smem[(k * 128 + tid) * 4] = xr[k];

  f32x2 acc1[8][2];
#pragma unroll
  for (int o = 0; o < 8; ++o) { acc1[o][0] = 0.f; acc1[o][1] = 0.f; }

  // ---- stage 1: 8 chunks of 16 channels
  for (int ch = 0; ch < 8; ++ch) {
    __syncthreads();                 // buf[ch&1] fully staged
    float4 xn[4];
    if (ch < 7) {
#pragma unroll
      for (int k = 0; k < 4; ++k)
        xn[k] = *(const float4*)(xstage + (size_t)((ch + 1) * 16 + k * 4) * CHUNKF);
    }
    const float* sb = smem + (ch & 1) * 2048 + posw * 32 + u * 4;
    const uint* wb = w1d + (ch * 16) * 16 + oh * 4;
#pragma unroll
    for (int cc = 0; cc < 16; ++cc) {
      float4 xq = *(const float4*)(sb + cc * 128);
      uint4 wq = *(const uint4*)(wb + cc * 16);
      float w0 = __uint_as_float(wq.x << 16);
      float w1 = __uint_as_float(wq.x & 0xffff0000u);
      float w2 = __uint_as_float(wq.y << 16);
      float w3 = __uint_as_float(wq.y & 0xffff0000u);
      float w4 = __uint_as_float(wq.z << 16);
      float w5 = __uint_as_float(wq.z & 0xffff0000u);
      float w6 = __uint_as_float(wq.w << 16);
      float w7 = __uint_as_float(wq.w & 0xffff0000u);
      f32x2 xp0 = {xq.x, xq.y}, xp1 = {xq.z, xq.w};
      acc1[0][0] += xp0 * w0;  acc1[0][1] += xp1 * w0;
      acc1[1][0] += xp0 * w1;  acc1[1][1] += xp1 * w1;
      acc1[2][0] += xp0 * w2;  acc1[2][1] += xp1 * w2;
      acc1[3][0] += xp0 * w3;  acc1[3][1] += xp1 * w3;
      acc1[4][0] += xp0 * w4;  acc1[4][1] += xp1 * w4;
      acc1[5][0] += xp0 * w5;  acc1[5][1] += xp1 * w5;
      acc1[6][0] += xp0 * w6;  acc1[6][1] += xp1 * w6;
      acc1[7][0] += xp0 * w7;  acc1[7][1] += xp1 * w7;
    }
    if (ch < 7) {
#pragma unroll
      for (int k = 0; k < 4; ++k)
        *(float4*)&smem[((ch + 1) & 1) * 2048 + (k * 128 + tid) * 4] = xn[k];
    }
  }

  // ---- z -> LDS overlay (all stage-1 reads complete block-wide first)
  __syncthreads();
#pragma unroll
  for (int o = 0; o < 8; ++o) {
    int dw = posw * 1024 + (oh * 8 + o) * 32 + u * 4;
    *(float4*)&smem[dw] = make_float4(acc1[o][0][0], acc1[o][0][1],
                                      acc1[o][1][0], acc1[o][1][1]);
  }
  // wave reads only its own 2 positions below -> wave-synchronous, no barrier

  float kv[16];
#pragma unroll
  for (int o = 0; o < 16; ++o) kv[o] = kap[oq * 16 + o];

  // ---- stage 2 + epilogue, per owned position
#pragma unroll 1
  for (int pp = 0; pp < 2; ++pp) {
    const int pos = w * 2 + pp;
    f32x2 a2[16][2];
#pragma unroll
    for (int o = 0; o < 16; ++o) { a2[o][0] = 0.f; a2[o][1] = 0.f; }

    const float* zp = smem + pos * 1024 + u2 * 4;
    const uint* w2p = w2d + oq * 8;
#pragma unroll 4
    for (int j = 0; j < 32; ++j) {
      float4 zq = *(const float4*)(zp + j * 32);
      uint4 wa = *(const uint4*)(w2p + j * 64);
      uint4 wb = *(const uint4*)(w2p + j * 64 + 4);
      float wv[16];
      wv[0]  = __uint_as_float(wa.x << 16);
      wv[1]  = __uint_as_float(wa.x & 0xffff0000u);
      wv[2]  = __uint_as_float(wa.y << 16);
      wv[3]  = __uint_as_float(wa.y & 0xffff0000u);
      wv[4]  = __uint_as_float(wa.z << 16);
      wv[5]  = __uint_as_float(wa.z & 0xffff0000u);
      wv[6]  = __uint_as_float(wa.w << 16);
      wv[7]  = __uint_as_float(wa.w & 0xffff0000u);
      wv[8]  = __uint_as_float(wb.x << 16);
      wv[9]  = __uint_as_float(wb.x & 0xffff0000u);
      wv[10] = __uint_as_float(wb.y << 16);
      wv[11] = __uint_as_float(wb.y & 0xffff0000u);
      wv[12] = __uint_as_float(wb.z << 16);
      wv[13] = __uint_as_float(wb.z & 0xffff0000u);
      wv[14] = __uint_as_float(wb.w << 16);
      wv[15] = __uint_as_float(wb.w & 0xffff0000u);
      f32x2 zp0 = {zq.x, zq.y}, zp1 = {zq.z, zq.w};
#pragma unroll
      for (int o = 0; o < 16; ++o) {
        a2[o][0] += zp0 * wv[o];
        a2[o][1] += zp1 * wv[o];
      }
    }

    float* outb = out + (size_t)nb * CIN * CHUNKF + (size_t)(hw0 + pos) * 32 + u2 * 4;
#pragma unroll
    for (int o = 0; o < 16; ++o) {
      float c0 = a2[o][0][0];
      float c1 = c0 + a2[o][0][1];
      float c2 = c1 + a2[o][1][0];
      float c3 = c2 + a2[o][1][1];
      float run = c3;                // 8-lane (u2) inclusive prefix of quad sums
      float r1 = __shfl_up(run, 1); if (u2 >= 1) run += r1;
      float r2 = __shfl_up(run, 2); if (u2 >= 2) run += r2;
      float r4 = __shfl_up(run, 4); if (u2 >= 4) run += r4;
      float base = (run - c3) - kv[o];        // S[4u2-1] - kappa
      float prev = (u2 == 0) ? 0.f : fminf(fmaxf(base, -6.f), 6.f);
      float A0 = fminf(fmaxf(base + c0, -6.f), 6.f);
      float A1 = fminf(fmaxf(base + c1, -6.f), 6.f);
      float A2 = fminf(fmaxf(base + c2, -6.f), 6.f);
      float A3 = fminf(fmaxf(base + c3, -6.f), 6.f);
      float* op = outb + (size_t)(oq * 16 + o) * CHUNKF;
      *(float4*)op = make_float4(A0 - prev, A1 - A0, A2 - A1, A3 - A2);
    }
  }
}

extern "C" void kernel_launch(void* const* d_in, const int* in_sizes, int n_in,
                              void* d_out, int out_size, void* d_ws, size_t ws_size,
                              hipStream_t stream) {
  const float* x  = (const float*)d_in[0];
  const float* v1 = (const float*)d_in[1];
  const float* g1 = (const float*)d_in[2];
  const float* v2 = (const float*)d_in[3];
  const float* g2 = (const float*)d_in[4];
  float* ws  = (float*)d_ws;
  float* out = (float*)d_out;

  hipMemsetAsync(ws + 8192, 0, 128 * sizeof(float), stream);
  wnorm_mean_kernel<<<2208, 256, 0, stream>>>(x, v1, g1, v2, g2, ws);
  kappa_kernel<<<1, 128, 0, stream>>>(ws);
  fused_kernel<<<1024, 128, 0, stream>>>(x, ws, out);
}

// Round 11
// 51.019 us; speedup vs baseline: 1.2813x; 1.2813x over previous
//
#include <hip/hip_runtime.h>

// Dims fixed by reference setup_inputs
#define CIN  128
#define CHUNKF 32768       // HW*T floats per (n, channel)

typedef float f32x4 __attribute__((ext_vector_type(4)));
typedef short s16x8 __attribute__((ext_vector_type(8)));

// ws float layout:
// [0,4096)      qw1   [32][128] f32   (kappa input)
// [4096,8192)   qw2   [128][32] f32   (kappa input)
// [8192,8320)   msum  [128]
// [8320,8448)   kappa [128]
// [8448,10496)  qw1bf [32 o1][128 c] bf16 (ushort, 4096 = 2048 floats)
// [10496,12544) qw2bf [128 o2][32 j] bf16 (ushort, 4096 = 2048 floats)
//   (round-8 bug: qw2bf was at 9472, overlapping qw1bf's upper half)

__device__ __forceinline__ uint pack_hilo(float f) {
  // u32 = bf16(hi) in low16 | bf16(lo) in high16 ; hi = trunc-to-bf16, lo = trunc(f - hi)
  uint b = __float_as_uint(f);
  uint hi = b & 0xffff0000u;
  float lo = f - __uint_as_float(hi);
  return (hi >> 16) | (__float_as_uint(lo) & 0xffff0000u);
}

// blocks [0,2048): mean partial sums; blocks [2048,2208): weight-norm rows.
__global__ __launch_bounds__(256) void wnorm_mean_kernel(
    const float* __restrict__ x,
    const float* __restrict__ v1, const float* __restrict__ g1,
    const float* __restrict__ v2, const float* __restrict__ g2,
    float* __restrict__ ws) {
  int tid = threadIdx.x;
  if (blockIdx.x < 2048) {
    int b = blockIdx.x;
    int chunk = b >> 2, quarter = b & 3;      // chunk = n*128 + i
    int i = chunk & 127;
    const float4* xp = (const float4*)(x + (size_t)chunk * CHUNKF + (size_t)quarter * 8192);
    float acc = 0.f;
#pragma unroll
    for (int it = 0; it < 8; ++it) {
      int f4i = tid + 256 * it;
      float4 v = xp[f4i];
      int t0 = (4 * f4i) & 31;
      acc += v.x * (float)(32 - t0) + v.y * (float)(31 - t0)
           + v.z * (float)(30 - t0) + v.w * (float)(29 - t0);
    }
    for (int off = 32; off >= 1; off >>= 1) acc += __shfl_down(acc, off);
    __shared__ float part[4];
    if ((tid & 63) == 0) part[tid >> 6] = acc;
    __syncthreads();
    if (tid == 0) atomicAdd(&ws[8192 + i], part[0] + part[1] + part[2] + part[3]);
  } else {
    int b = blockIdx.x - 2048;
    bool first = (b < 32);
    int row = first ? b : b - 32;
    int len = first ? 128 : 32;
    const float* v = first ? v1 : v2;
    const float* g = first ? g1 : g2;

    double val = 0.0;
    if (tid < len) { double t = (double)v[row * len + tid]; val = t * t; }
    for (int off = 32; off >= 1; off >>= 1) val += __shfl_down(val, off);
    __shared__ double partial[4];
    if ((tid & 63) == 0) partial[tid >> 6] = val;
    __syncthreads();
    double norm = sqrt(partial[0] + partial[1]);
    if (tid < len) {
      double w = (double)g[row] * (double)v[row * len + tid] / norm;
      double qd = rint(w * 32.0) * 0.03125;        // step = 2/64, round-half-even
      qd = fmin(fmax(qd, -2.0), 1.984375);
      float qf = (float)qd;                        // exactly representable in bf16
      ushort bf = (ushort)(__float_as_uint(qf) >> 16);
      if (first) {                                 // row=o1, tid=c
        ws[row * 128 + tid] = qf;                            // qw1 f32
        ((ushort*)(ws + 8448))[row * 128 + tid] = bf;        // qw1bf [o1][c]
      } else {                                     // row=o2, tid=j
        ws[4096 + row * 32 + tid] = qf;                      // qw2 f32
        ((ushort*)(ws + 10496))[row * 32 + tid] = bf;        // qw2bf [o2][j]
      }
    }
  }
}

// kappa[o2] = sum_j qw2[o2][j] * (sum_c qw1[j][c] * mbar[c])
__global__ __launch_bounds__(128) void kappa_kernel(float* __restrict__ ws) {
  __shared__ float z[32];
  int tid = threadIdx.x;
  const float* qw1 = ws;
  const float* qw2 = ws + 4096;
  const float* msum = ws + 8192;
  if (tid < 32) {
    float acc = 0.f;
    for (int c = 0; c < 128; ++c) acc += qw1[tid * 128 + c] * msum[c];
    z[tid] = acc * (1.0f / 131072.0f);
  }
  __syncthreads();
  float k = 0.f;
  for (int j = 0; j < 32; ++j) k += qw2[tid * 32 + j] * z[j];
  ws[8320 + tid] = k;
}

// MFMA fused kernel (round-8 design, weight-table offsets fixed).
// Block = 4 waves, wave wv owns position hw0+wv.
// Stage 1 (MFMA 16x16x32 bf16): z[j][n] = sum_c qw1[j][c] * x[c][n]
//   A = qw1 (bf16-exact, from global), B = x (hi/lo split, packed u32 in LDS).
// Stage 2 (swapped): D'[t][o2] = sum_j z^T[t][j] * qw2^T[j][o2]
//   A = z^T (hi/lo from wave-private LDS), B = qw2 (bf16-exact, global).
// Epilogue on t-major D': in-lane quad cumsum + masked shfl prefix over g,
// clip(S - kappa), diff, float4 stores.
__global__ __launch_bounds__(256, 2) void fused_kernel(
    const float* __restrict__ x, const float* __restrict__ ws,
    float* __restrict__ out) {
  const ushort* qw1bf = (const ushort*)(ws + 8448);    // [32 j][128 c]
  const ushort* qw2bf = (const ushort*)(ws + 10496);   // [128 o2][32 j]
  const float* kap = ws + 8320;

  __shared__ uint xs[8192];   // [64 c][32 units][4 u32] packed hi|lo, XOR-swizzled
  __shared__ uint zs[4096];   // per wave 1024: [32 n][8 units][4 u32] packed hi|lo

  const int tid = threadIdx.x;
  const int wv = tid >> 6;
  const int l  = tid & 63;
  const int g  = l >> 4;        // 0..3
  const int ln = l & 15;        // 0..15

  const int nb  = blockIdx.x >> 8;
  const int hw0 = (blockIdx.x & 255) * 4;
  const float* xblk = x + (size_t)nb * CIN * CHUNKF + (size_t)hw0 * 32;

  // ---- weight fragments + kappa from global (L1/L2-hot tables)
  s16x8 A1[2][4];               // [jt][Kst]: A[m=j][k=c], m=jt*16+ln, k=Kst*32+g*8+i
#pragma unroll
  for (int jt = 0; jt < 2; ++jt)
#pragma unroll
    for (int ks = 0; ks < 4; ++ks)
      A1[jt][ks] = *(const s16x8*)(qw1bf + (jt * 16 + ln) * 128 + ks * 32 + g * 8);
  s16x8 B2[8];                  // [Nt]: B[k=j][n=o2], n=Nt*16+ln, k=g*8+i
  float kv[8];
#pragma unroll
  for (int nt = 0; nt < 8; ++nt) {
    B2[nt] = *(const s16x8*)(qw2bf + (nt * 16 + ln) * 32 + g * 8);
    kv[nt] = kap[nt * 16 + ln];
  }

  // ---- issue phase-0 x loads (c 0..63, all 128 n)
  float4 xr[8];
#pragma unroll
  for (int k = 0; k < 8; ++k) {
    int f = k * 256 + tid, c = f >> 5, n4 = f & 31;
    xr[k] = *(const float4*)(xblk + (size_t)c * CHUNKF + n4 * 4);
  }

  f32x4 acc1[2][2];             // [jt][nt] : z[j=jt*16+g*4+r][n=wv*32+nt*16+ln]
#pragma unroll
  for (int a = 0; a < 2; ++a)
#pragma unroll
    for (int b = 0; b < 2; ++b) acc1[a][b] = (f32x4){0.f, 0.f, 0.f, 0.f};

#pragma unroll
  for (int ph = 0; ph < 2; ++ph) {
    // pack hi|lo and stage into xs (swizzled unit = n4 ^ ((c>>2)&6))
#pragma unroll
    for (int k = 0; k < 8; ++k) {
      int f = k * 256 + tid, c = f >> 5, n4 = f & 31;
      int u = n4 ^ ((c >> 2) & 6);
      uint4 pk;
      pk.x = pack_hilo(xr[k].x); pk.y = pack_hilo(xr[k].y);
      pk.z = pack_hilo(xr[k].z); pk.w = pack_hilo(xr[k].w);
      *(uint4*)&xs[c * 128 + u * 4] = pk;
    }
    __syncthreads();
    if (ph == 0) {               // issue phase-1 loads; covered by phase-0 MFMA work
#pragma unroll
      for (int k = 0; k < 8; ++k) {
        int f = k * 256 + tid, c = f >> 5, n4 = f & 31;
        xr[k] = *(const float4*)(xblk + (size_t)(64 + c) * CHUNKF + n4 * 4);
      }
    }
    // MFMA: Ksteps {2ph, 2ph+1}
#pragma unroll
    for (int kl = 0; kl < 2; ++kl) {
#pragma unroll
      for (int nt = 0; nt < 2; ++nt) {
        const int n = wv * 32 + nt * 16 + ln;
        uint q0, q1, q2, q3, q4, q5, q6, q7;
        {
          const int base = (kl * 32 + g * 8) * 128;
          const int u = ((n >> 2) ^ (((kl * 32 + g * 8) >> 2) & 6)) * 4 + (n & 3);
          q0 = xs[base + 0 * 128 + u]; q1 = xs[base + 1 * 128 + u];
          q2 = xs[base + 2 * 128 + u]; q3 = xs[base + 3 * 128 + u];
          // i>=4 flips bit0 of (c>>2), which (&6) drops -> same u
          q4 = xs[base + 4 * 128 + u]; q5 = xs[base + 5 * 128 + u];
          q6 = xs[base + 6 * 128 + u]; q7 = xs[base + 7 * 128 + u];
        }
        uint4 H, L;
        H.x = (q0 & 0xffffu) | (q1 << 16);  H.y = (q2 & 0xffffu) | (q3 << 16);
        H.z = (q4 & 0xffffu) | (q5 << 16);  H.w = (q6 & 0xffffu) | (q7 << 16);
        L.x = (q0 >> 16) | (q1 & 0xffff0000u); L.y = (q2 >> 16) | (q3 & 0xffff0000u);
        L.z = (q4 >> 16) | (q5 & 0xffff0000u); L.w = (q6 >> 16) | (q7 & 0xffff0000u);
        s16x8 Bh = __builtin_bit_cast(s16x8, H);
        s16x8 Bl = __builtin_bit_cast(s16x8, L);
#pragma unroll
        for (int jt = 0; jt < 2; ++jt) {
          acc1[jt][nt] = __builtin_amdgcn_mfma_f32_16x16x32_bf16(
              A1[jt][ph * 2 + kl], Bh, acc1[jt][nt], 0, 0, 0);
          acc1[jt][nt] = __builtin_amdgcn_mfma_f32_16x16x32_bf16(
              A1[jt][ph * 2 + kl], Bl, acc1[jt][nt], 0, 0, 0);
        }
      }
    }
    if (ph == 0) __syncthreads();   // all waves done reading xs before restage
  }

  // ---- z -> wave-private zs (packed hi|lo, swizzled); wave-synchronous
  uint* zw = zs + wv * 1024;
#pragma unroll
  for (int jt = 0; jt < 2; ++jt)
#pragma unroll
    for (int nt = 0; nt < 2; ++nt) {
      int n = nt * 16 + ln;
      int u = (jt * 4 + g) ^ (n & 7);
      uint4 pk;
      pk.x = pack_hilo(acc1[jt][nt][0]);
      pk.y = pack_hilo(acc1[jt][nt][1]);
      pk.z = pack_hilo(acc1[jt][nt][2]);
      pk.w = pack_hilo(acc1[jt][nt][3]);
      *(uint4*)&zw[n * 32 + u * 4] = pk;
    }

  // ---- stage 2: D'[t][o2], acc2[Nt][Mt]
  f32x4 acc2[8][2];
#pragma unroll
  for (int a = 0; a < 8; ++a)
#pragma unroll
    for (int b = 0; b < 2; ++b) acc2[a][b] = (f32x4){0.f, 0.f, 0.f, 0.f};

#pragma unroll
  for (int mt = 0; mt < 2; ++mt) {
    int n = mt * 16 + ln;                  // t-row of A' = z^T
    int u0 = (2 * g) ^ (n & 7);
    int u1 = (2 * g + 1) ^ (n & 7);
    uint4 qa = *(const uint4*)&zw[n * 32 + u0 * 4];
    uint4 qb = *(const uint4*)&zw[n * 32 + u1 * 4];
    uint4 H, L;
    H.x = (qa.x & 0xffffu) | (qa.y << 16);  H.y = (qa.z & 0xffffu) | (qa.w << 16);
    H.z = (qb.x & 0xffffu) | (qb.y << 16);  H.w = (qb.z & 0xffffu) | (qb.w << 16);
    L.x = (qa.x >> 16) | (qa.y & 0xffff0000u); L.y = (qa.z >> 16) | (qa.w & 0xffff0000u);
    L.z = (qb.x >> 16) | (qb.y & 0xffff0000u); L.w = (qb.z >> 16) | (qb.w & 0xffff0000u);
    s16x8 Ah = __builtin_bit_cast(s16x8, H);
    s16x8 Al = __builtin_bit_cast(s16x8, L);
#pragma unroll
    for (int nt = 0; nt < 8; ++nt) {
      acc2[nt][mt] = __builtin_amdgcn_mfma_f32_16x16x32_bf16(Ah, B2[nt], acc2[nt][mt], 0, 0, 0);
      acc2[nt][mt] = __builtin_amdgcn_mfma_f32_16x16x32_bf16(Al, B2[nt], acc2[nt][mt], 0, 0, 0);
    }
  }

  // ---- epilogue: lane holds t = mt*16 + g*4 + r for o2 = nt*16 + ln
  const size_t outbase = (size_t)nb * CIN * CHUNKF + (size_t)(hw0 + wv) * 32;
#pragma unroll
  for (int nt = 0; nt < 8; ++nt) {
    float c0[2], c1[2], c2[2], c3[2], base[2], Qi0 = 0.f;
#pragma unroll
    for (int mt = 0; mt < 2; ++mt) {
      c0[mt] = acc2[nt][mt][0];
      c1[mt] = c0[mt] + acc2[nt][mt][1];
      c2[mt] = c1[mt] + acc2[nt][mt][2];
      c3[mt] = c2[mt] + acc2[nt][mt][3];
      float Qi = c3[mt];
      float t1 = __shfl_up(Qi, 16); if (g >= 1) Qi += t1;
      float t2 = __shfl_up(Qi, 32); if (g >= 2) Qi += t2;
      base[mt] = Qi - c3[mt];          // exclusive prefix over g
      if (mt == 0) Qi0 = Qi;
    }
    float S0tot = __shfl(Qi0, 48 + ln);  // full Mt0 (t=0..15) sum for this o2
    base[1] += S0tot;
    const float kpp = kv[nt];
    float* op = out + outbase + (size_t)(nt * 16 + ln) * CHUNKF;
#pragma unroll
    for (int mt = 0; mt < 2; ++mt) {
      float Bv = base[mt] - kpp;
      float prev = fminf(fmaxf(Bv, -6.f), 6.f);
      if (mt == 0 && g == 0) prev = 0.f;           // t = 0 boundary
      float A0 = fminf(fmaxf(Bv + c0[mt], -6.f), 6.f);
      float A1v = fminf(fmaxf(Bv + c1[mt], -6.f), 6.f);
      float A2v = fminf(fmaxf(Bv + c2[mt], -6.f), 6.f);
      float A3v = fminf(fmaxf(Bv + c3[mt], -6.f), 6.f);
      *(float4*)(op + mt * 16 + g * 4) =
          make_float4(A0 - prev, A1v - A0, A2v - A1v, A3v - A2v);
    }
  }
}

extern "C" void kernel_launch(void* const* d_in, const int* in_sizes, int n_in,
                              void* d_out, int out_size, void* d_ws, size_t ws_size,
                              hipStream_t stream) {
  const float* x  = (const float*)d_in[0];
  const float* v1 = (const float*)d_in[1];
  const float* g1 = (const float*)d_in[2];
  const float* v2 = (const float*)d_in[3];
  const float* g2 = (const float*)d_in[4];
  float* ws  = (float*)d_ws;
  float* out = (float*)d_out;

  hipMemsetAsync(ws + 8192, 0, 128 * sizeof(float), stream);
  wnorm_mean_kernel<<<2208, 256, 0, stream>>>(x, v1, g1, v2, g2, ws);
  kappa_kernel<<<1, 128, 0, stream>>>(ws);
  fused_kernel<<<1024, 256, 0, stream>>>(x, ws, out);
}

// Round 12
// 49.386 us; speedup vs baseline: 1.3237x; 1.0331x over previous
//
#include <hip/hip_runtime.h>

// Dims fixed by reference setup_inputs
#define CIN  128
#define CHUNKF 32768       // HW*T floats per (n, channel)

typedef float f32x4 __attribute__((ext_vector_type(4)));
typedef short s16x8 __attribute__((ext_vector_type(8)));

// ws float layout:
// [0,4096)      qw1   [32][128] f32   (kappa input)
// [4096,8192)   qw2   [128][32] f32   (kappa input, [o2][j])
// [8192,8320)   msum  [128]
// [8448,10496)  qw1bf [32 o1][128 c] bf16 (ushort)
// [10496,12544) qw2bf [128 o2][32 j] bf16 (ushort)

__device__ __forceinline__ uint pack_hilo(float f) {
  // u32 = bf16(hi) in low16 | bf16(lo) in high16 ; hi = trunc-to-bf16
  uint b = __float_as_uint(f);
  uint hi = b & 0xffff0000u;
  float lo = f - __uint_as_float(hi);
  return (hi >> 16) | (__float_as_uint(lo) & 0xffff0000u);
}

// blocks [0,2048): mean partial sums; blocks [2048,2208): weight-norm rows.
__global__ __launch_bounds__(256) void wnorm_mean_kernel(
    const float* __restrict__ x,
    const float* __restrict__ v1, const float* __restrict__ g1,
    const float* __restrict__ v2, const float* __restrict__ g2,
    float* __restrict__ ws) {
  int tid = threadIdx.x;
  if (blockIdx.x < 2048) {
    int b = blockIdx.x;
    int chunk = b >> 2, quarter = b & 3;      // chunk = n*128 + i
    int i = chunk & 127;
    const float4* xp = (const float4*)(x + (size_t)chunk * CHUNKF + (size_t)quarter * 8192);
    float acc = 0.f;
#pragma unroll
    for (int it = 0; it < 8; ++it) {
      int f4i = tid + 256 * it;
      float4 v = xp[f4i];
      int t0 = (4 * f4i) & 31;
      acc += v.x * (float)(32 - t0) + v.y * (float)(31 - t0)
           + v.z * (float)(30 - t0) + v.w * (float)(29 - t0);
    }
    for (int off = 32; off >= 1; off >>= 1) acc += __shfl_down(acc, off);
    __shared__ float part[4];
    if ((tid & 63) == 0) part[tid >> 6] = acc;
    __syncthreads();
    if (tid == 0) atomicAdd(&ws[8192 + i], part[0] + part[1] + part[2] + part[3]);
  } else {
    int b = blockIdx.x - 2048;
    bool first = (b < 32);
    int row = first ? b : b - 32;
    int len = first ? 128 : 32;
    const float* v = first ? v1 : v2;
    const float* g = first ? g1 : g2;

    double val = 0.0;
    if (tid < len) { double t = (double)v[row * len + tid]; val = t * t; }
    for (int off = 32; off >= 1; off >>= 1) val += __shfl_down(val, off);
    __shared__ double partial[4];
    if ((tid & 63) == 0) partial[tid >> 6] = val;
    __syncthreads();
    double norm = sqrt(partial[0] + partial[1]);
    if (tid < len) {
      double w = (double)g[row] * (double)v[row * len + tid] / norm;
      double qd = rint(w * 32.0) * 0.03125;        // step = 2/64, round-half-even
      qd = fmin(fmax(qd, -2.0), 1.984375);
      float qf = (float)qd;                        // exactly representable in bf16
      ushort bf = (ushort)(__float_as_uint(qf) >> 16);
      if (first) {                                 // row=o1, tid=c
        ws[row * 128 + tid] = qf;                            // qw1 f32
        ((ushort*)(ws + 8448))[row * 128 + tid] = bf;        // qw1bf [o1][c]
      } else {                                     // row=o2, tid=j
        ws[4096 + row * 32 + tid] = qf;                      // qw2 f32 [o2][j]
        ((ushort*)(ws + 10496))[row * 32 + tid] = bf;        // qw2bf [o2][j]
      }
    }
  }
}

// MFMA fused kernel (round-11 design + occupancy restructure + in-block kappa).
// Block = 4 waves, wave wv owns position hw0+wv. 4 blocks/CU target.
// Stage 1 (MFMA 16x16x32 bf16): z[j][n] = sum_c qw1[j][c] * x[c][n]
// Stage 2 (swapped): D'[t][o2] = sum_j z^T[t][j] * qw2^T[j][o2], in 2 halves.
// Epilogue: in-lane quad cumsum + masked shfl prefix, clip(S-kappa), diff.
__global__ __launch_bounds__(256, 4) void fused_kernel(
    const float* __restrict__ x, const float* __restrict__ ws,
    float* __restrict__ out) {
  const ushort* qw1bf = (const ushort*)(ws + 8448);    // [32 j][128 c]
  const ushort* qw2bf = (const ushort*)(ws + 10496);   // [128 o2][32 j]

  __shared__ uint xs[8192];     // 32 KB; z overlays xs[0,4096) after barrier
  __shared__ float zred[288];   // kappa partials [32j][8g] + zsm[32]
  __shared__ float kls[128];    // kappa result

  const int tid = threadIdx.x;
  const int wv = tid >> 6;
  const int l  = tid & 63;
  const int g  = l >> 4;        // 0..3
  const int ln = l & 15;        // 0..15

  const int nb  = blockIdx.x >> 8;
  const int hw0 = (blockIdx.x & 255) * 4;
  const float* xblk = x + (size_t)nb * CIN * CHUNKF + (size_t)hw0 * 32;

  // ---- issue phase-0 x loads first (cover kappa + weight loads below)
  float4 xr[8];
#pragma unroll
  for (int k = 0; k < 8; ++k) {
    int f = k * 256 + tid, c = f >> 5, n4 = f & 31;
    xr[k] = *(const float4*)(xblk + (size_t)c * CHUNKF + n4 * 4);
  }

  // ---- stage-1 A fragments (qw1 bf16-exact, L2-hot global)
  s16x8 A1[2][4];               // [jt][Kst]: m=jt*16+ln, k=Kst*32+g*8+i
#pragma unroll
  for (int jt = 0; jt < 2; ++jt)
#pragma unroll
    for (int ks = 0; ks < 4; ++ks)
      A1[jt][ks] = *(const s16x8*)(qw1bf + (jt * 16 + ln) * 128 + ks * 32 + g * 8);

  // ---- in-block kappa (r4-proven reduce; covered by x-load latency)
  {
    int j = tid & 31, grp = tid >> 5;
    const float* qr = ws + j * 128 + grp * 16;
    const float* mr = ws + 8192 + grp * 16;
    float pp = 0.f;
#pragma unroll
    for (int cc = 0; cc < 16; ++cc) pp += qr[cc] * mr[cc];
    zred[j * 8 + grp] = pp;
  }
  __syncthreads();
  if (tid < 32) {
    float t = 0.f;
#pragma unroll
    for (int gg = 0; gg < 8; ++gg) t += zred[tid * 8 + gg];
    zred[256 + tid] = t * (1.0f / 131072.0f);
  }
  __syncthreads();
  if (tid < 128) {
    const float* q2 = ws + 4096 + tid * 32;
    float kk = 0.f;
#pragma unroll 8
    for (int j = 0; j < 32; ++j) kk += q2[j] * zred[256 + j];
    kls[tid] = kk;
  }
  // kls consumed in epilogue — separated by multiple barriers below

  f32x4 acc1[2][2];             // [jt][nt]: z[j=jt*16+g*4+r][n=wv*32+nt*16+ln]
#pragma unroll
  for (int a = 0; a < 2; ++a)
#pragma unroll
    for (int b = 0; b < 2; ++b) acc1[a][b] = (f32x4){0.f, 0.f, 0.f, 0.f};

#pragma unroll
  for (int ph = 0; ph < 2; ++ph) {
    // pack hi|lo and stage into xs (swizzled unit = n4 ^ ((c>>2)&6))
#pragma unroll
    for (int k = 0; k < 8; ++k) {
      int f = k * 256 + tid, c = f >> 5, n4 = f & 31;
      int u = n4 ^ ((c >> 2) & 6);
      uint4 pk;
      pk.x = pack_hilo(xr[k].x); pk.y = pack_hilo(xr[k].y);
      pk.z = pack_hilo(xr[k].z); pk.w = pack_hilo(xr[k].w);
      *(uint4*)&xs[c * 128 + u * 4] = pk;
    }
    __syncthreads();
    if (ph == 0) {               // issue phase-1 loads; covered by phase-0 MFMAs
#pragma unroll
      for (int k = 0; k < 8; ++k) {
        int f = k * 256 + tid, c = f >> 5, n4 = f & 31;
        xr[k] = *(const float4*)(xblk + (size_t)(64 + c) * CHUNKF + n4 * 4);
      }
    }
    // MFMA: Ksteps {2ph, 2ph+1}
#pragma unroll
    for (int kl = 0; kl < 2; ++kl) {
#pragma unroll
      for (int nt = 0; nt < 2; ++nt) {
        const int n = wv * 32 + nt * 16 + ln;
        uint q0, q1, q2, q3, q4, q5, q6, q7;
        {
          const int base = (kl * 32 + g * 8) * 128;
          const int u = ((n >> 2) ^ (((kl * 32 + g * 8) >> 2) & 6)) * 4 + (n & 3);
          q0 = xs[base + 0 * 128 + u]; q1 = xs[base + 1 * 128 + u];
          q2 = xs[base + 2 * 128 + u]; q3 = xs[base + 3 * 128 + u];
          q4 = xs[base + 4 * 128 + u]; q5 = xs[base + 5 * 128 + u];
          q6 = xs[base + 6 * 128 + u]; q7 = xs[base + 7 * 128 + u];
        }
        uint4 H, L;
        H.x = (q0 & 0xffffu) | (q1 << 16);  H.y = (q2 & 0xffffu) | (q3 << 16);
        H.z = (q4 & 0xffffu) | (q5 << 16);  H.w = (q6 & 0xffffu) | (q7 << 16);
        L.x = (q0 >> 16) | (q1 & 0xffff0000u); L.y = (q2 >> 16) | (q3 & 0xffff0000u);
        L.z = (q4 >> 16) | (q5 & 0xffff0000u); L.w = (q6 >> 16) | (q7 & 0xffff0000u);
        s16x8 Bh = __builtin_bit_cast(s16x8, H);
        s16x8 Bl = __builtin_bit_cast(s16x8, L);
#pragma unroll
        for (int jt = 0; jt < 2; ++jt) {
          acc1[jt][nt] = __builtin_amdgcn_mfma_f32_16x16x32_bf16(
              A1[jt][ph * 2 + kl], Bh, acc1[jt][nt], 0, 0, 0);
          acc1[jt][nt] = __builtin_amdgcn_mfma_f32_16x16x32_bf16(
              A1[jt][ph * 2 + kl], Bl, acc1[jt][nt], 0, 0, 0);
        }
      }
    }
    __syncthreads();   // ph0: before restage; ph1: before z-overlay write
  }

  // ---- z -> wave-private slab overlaying xs (barrier above protects xs reads)
  uint* zw = xs + wv * 1024;
#pragma unroll
  for (int jt = 0; jt < 2; ++jt)
#pragma unroll
    for (int nt = 0; nt < 2; ++nt) {
      int n = nt * 16 + ln;
      int u = (jt * 4 + g) ^ (n & 7);
      uint4 pk;
      pk.x = pack_hilo(acc1[jt][nt][0]);
      pk.y = pack_hilo(acc1[jt][nt][1]);
      pk.z = pack_hilo(acc1[jt][nt][2]);
      pk.w = pack_hilo(acc1[jt][nt][3]);
      *(uint4*)&zw[n * 32 + u * 4] = pk;
    }

  // ---- stage-2 A fragments (z^T, hi/lo) built once
  s16x8 Ah[2], Al[2];
#pragma unroll
  for (int mt = 0; mt < 2; ++mt) {
    int n = mt * 16 + ln;                  // t-row of A' = z^T
    int u0 = (2 * g) ^ (n & 7);
    int u1 = (2 * g + 1) ^ (n & 7);
    uint4 qa = *(const uint4*)&zw[n * 32 + u0 * 4];
    uint4 qb = *(const uint4*)&zw[n * 32 + u1 * 4];
    uint4 H, L;
    H.x = (qa.x & 0xffffu) | (qa.y << 16);  H.y = (qa.z & 0xffffu) | (qa.w << 16);
    H.z = (qb.x & 0xffffu) | (qb.y << 16);  H.w = (qb.z & 0xffffu) | (qb.w << 16);
    L.x = (qa.x >> 16) | (qa.y & 0xffff0000u); L.y = (qa.z >> 16) | (qa.w & 0xffff0000u);
    L.z = (qb.x >> 16) | (qb.y & 0xffff0000u); L.w = (qb.z >> 16) | (qb.w & 0xffff0000u);
    Ah[mt] = __builtin_bit_cast(s16x8, H);
    Al[mt] = __builtin_bit_cast(s16x8, L);
  }

  // ---- stage 2 + epilogue in two halves of 4 nt (VGPR control)
  const size_t outbase = (size_t)nb * CIN * CHUNKF + (size_t)(hw0 + wv) * 32;
#pragma unroll 1
  for (int h = 0; h < 2; ++h) {
    s16x8 B2[4];
#pragma unroll
    for (int q = 0; q < 4; ++q)
      B2[q] = *(const s16x8*)(qw2bf + ((h * 4 + q) * 16 + ln) * 32 + g * 8);

    f32x4 acc2[4][2];
#pragma unroll
    for (int a = 0; a < 4; ++a)
#pragma unroll
      for (int b = 0; b < 2; ++b) acc2[a][b] = (f32x4){0.f, 0.f, 0.f, 0.f};

#pragma unroll
    for (int mt = 0; mt < 2; ++mt)
#pragma unroll
      for (int q = 0; q < 4; ++q) {
        acc2[q][mt] = __builtin_amdgcn_mfma_f32_16x16x32_bf16(Ah[mt], B2[q], acc2[q][mt], 0, 0, 0);
        acc2[q][mt] = __builtin_amdgcn_mfma_f32_16x16x32_bf16(Al[mt], B2[q], acc2[q][mt], 0, 0, 0);
      }

#pragma unroll
    for (int q = 0; q < 4; ++q) {
      const int nt = h * 4 + q;
      float c0[2], c1[2], c2[2], c3[2], base[2], Qi0 = 0.f;
#pragma unroll
      for (int mt = 0; mt < 2; ++mt) {
        c0[mt] = acc2[q][mt][0];
        c1[mt] = c0[mt] + acc2[q][mt][1];
        c2[mt] = c1[mt] + acc2[q][mt][2];
        c3[mt] = c2[mt] + acc2[q][mt][3];
        float Qi = c3[mt];
        float t1 = __shfl_up(Qi, 16); if (g >= 1) Qi += t1;
        float t2 = __shfl_up(Qi, 32); if (g >= 2) Qi += t2;
        base[mt] = Qi - c3[mt];          // exclusive prefix over g
        if (mt == 0) Qi0 = Qi;
      }
      float S0tot = __shfl(Qi0, 48 + ln);  // full t=0..15 sum for this o2
      base[1] += S0tot;
      const float kpp = kls[nt * 16 + ln];
      float* op = out + outbase + (size_t)(nt * 16 + ln) * CHUNKF;
#pragma unroll
      for (int mt = 0; mt < 2; ++mt) {
        float Bv = base[mt] - kpp;
        float prev = fminf(fmaxf(Bv, -6.f), 6.f);
        if (mt == 0 && g == 0) prev = 0.f;           // t = 0 boundary
        float A0 = fminf(fmaxf(Bv + c0[mt], -6.f), 6.f);
        float A1v = fminf(fmaxf(Bv + c1[mt], -6.f), 6.f);
        float A2v = fminf(fmaxf(Bv + c2[mt], -6.f), 6.f);
        float A3v = fminf(fmaxf(Bv + c3[mt], -6.f), 6.f);
        *(float4*)(op + mt * 16 + g * 4) =
            make_float4(A0 - prev, A1v - A0, A2v - A1v, A3v - A2v);
      }
    }
  }
}

extern "C" void kernel_launch(void* const* d_in, const int* in_sizes, int n_in,
                              void* d_out, int out_size, void* d_ws, size_t ws_size,
                              hipStream_t stream) {
  const float* x  = (const float*)d_in[0];
  const float* v1 = (const float*)d_in[1];
  const float* g1 = (const float*)d_in[2];
  const float* v2 = (const float*)d_in[3];
  const float* g2 = (const float*)d_in[4];
  float* ws  = (float*)d_ws;
  float* out = (float*)d_out;

  hipMemsetAsync(ws + 8192, 0, 128 * sizeof(float), stream);
  wnorm_mean_kernel<<<2208, 256, 0, stream>>>(x, v1, g1, v2, g2, ws);
  fused_kernel<<<1024, 256, 0, stream>>>(x, ws, out);
}

// Round 14
// 49.275 us; speedup vs baseline: 1.3267x; 1.0022x over previous
//
#include <hip/hip_runtime.h>
#include <hip/hip_cooperative_groups.h>

namespace cg = cooperative_groups;

#define CIN  128
#define CHUNKF 32768       // HW*T floats per (n, channel)

typedef float f32x4 __attribute__((ext_vector_type(4)));
typedef short s16x8 __attribute__((ext_vector_type(8)));

// ws float layout (coop path):
// [0,4096)       qw1 f32 [32 o1][128 c]
// [4096,8192)    qw2 f32 [128 o2][32 j]
// [8192,12288)   msumP [32 slot][128 c] (atomic partials; memset to 0)
// [12544,14592)  qw1bf ushort[32][128]
// [14592,16640)  qw2bf ushort[128][32]
// Fallback path (r12) uses: msum at 8192 (128), qw1bf at 8448, qw2bf at 10496.

__device__ __forceinline__ uint pack_hilo(float f) {
  uint b = __float_as_uint(f);
  uint hi = b & 0xffff0000u;
  float lo = f - __uint_as_float(hi);
  return (hi >> 16) | (__float_as_uint(lo) & 0xffff0000u);
}

// ======================= FALLBACK (r12-proven) =======================
__global__ __launch_bounds__(256) void wnorm_mean_kernel(
    const float* __restrict__ x,
    const float* __restrict__ v1, const float* __restrict__ g1,
    const float* __restrict__ v2, const float* __restrict__ g2,
    float* __restrict__ ws) {
  int tid = threadIdx.x;
  if (blockIdx.x < 2048) {
    int b = blockIdx.x;
    int chunk = b >> 2, quarter = b & 3;
    int i = chunk & 127;
    const float4* xp = (const float4*)(x + (size_t)chunk * CHUNKF + (size_t)quarter * 8192);
    float acc = 0.f;
#pragma unroll
    for (int it = 0; it < 8; ++it) {
      int f4i = tid + 256 * it;
      float4 v = xp[f4i];
      int t0 = (4 * f4i) & 31;
      acc += v.x * (float)(32 - t0) + v.y * (float)(31 - t0)
           + v.z * (float)(30 - t0) + v.w * (float)(29 - t0);
    }
    for (int off = 32; off >= 1; off >>= 1) acc += __shfl_down(acc, off);
    __shared__ float part[4];
    if ((tid & 63) == 0) part[tid >> 6] = acc;
    __syncthreads();
    if (tid == 0) atomicAdd(&ws[8192 + i], part[0] + part[1] + part[2] + part[3]);
  } else {
    int b = blockIdx.x - 2048;
    bool first = (b < 32);
    int row = first ? b : b - 32;
    int len = first ? 128 : 32;
    const float* v = first ? v1 : v2;
    const float* g = first ? g1 : g2;
    double val = 0.0;
    if (tid < len) { double t = (double)v[row * len + tid]; val = t * t; }
    for (int off = 32; off >= 1; off >>= 1) val += __shfl_down(val, off);
    __shared__ double partial[4];
    if ((tid & 63) == 0) partial[tid >> 6] = val;
    __syncthreads();
    double norm = sqrt(partial[0] + partial[1]);
    if (tid < len) {
      double w = (double)g[row] * (double)v[row * len + tid] / norm;
      double qd = rint(w * 32.0) * 0.03125;
      qd = fmin(fmax(qd, -2.0), 1.984375);
      float qf = (float)qd;
      ushort bf = (ushort)(__float_as_uint(qf) >> 16);
      if (first) {
        ws[row * 128 + tid] = qf;
        ((ushort*)(ws + 8448))[row * 128 + tid] = bf;
      } else {
        ws[4096 + row * 32 + tid] = qf;
        ((ushort*)(ws + 10496))[row * 32 + tid] = bf;
      }
    }
  }
}

__global__ __launch_bounds__(256, 4) void fused_kernel(
    const float* __restrict__ x, const float* __restrict__ ws,
    float* __restrict__ out) {
  const ushort* qw1bf = (const ushort*)(ws + 8448);
  const ushort* qw2bf = (const ushort*)(ws + 10496);

  __shared__ uint xs[8192];
  __shared__ float zred[288];
  __shared__ float kls[128];

  const int tid = threadIdx.x;
  const int wv = tid >> 6;
  const int l  = tid & 63;
  const int g  = l >> 4;
  const int ln = l & 15;

  const int nb  = blockIdx.x >> 8;
  const int hw0 = (blockIdx.x & 255) * 4;
  const float* xblk = x + (size_t)nb * CIN * CHUNKF + (size_t)hw0 * 32;

  float4 xr[8];
#pragma unroll
  for (int k = 0; k < 8; ++k) {
    int f = k * 256 + tid, c = f >> 5, n4 = f & 31;
    xr[k] = *(const float4*)(xblk + (size_t)c * CHUNKF + n4 * 4);
  }

  s16x8 A1[2][4];
#pragma unroll
  for (int jt = 0; jt < 2; ++jt)
#pragma unroll
    for (int ks = 0; ks < 4; ++ks)
      A1[jt][ks] = *(const s16x8*)(qw1bf + (jt * 16 + ln) * 128 + ks * 32 + g * 8);

  {
    int j = tid & 31, grp = tid >> 5;
    const float* qr = ws + j * 128 + grp * 16;
    const float* mr = ws + 8192 + grp * 16;
    float pp = 0.f;
#pragma unroll
    for (int cc = 0; cc < 16; ++cc) pp += qr[cc] * mr[cc];
    zred[j * 8 + grp] = pp;
  }
  __syncthreads();
  if (tid < 32) {
    float t = 0.f;
#pragma unroll
    for (int gg = 0; gg < 8; ++gg) t += zred[tid * 8 + gg];
    zred[256 + tid] = t * (1.0f / 131072.0f);
  }
  __syncthreads();
  if (tid < 128) {
    const float* q2 = ws + 4096 + tid * 32;
    float kk = 0.f;
#pragma unroll 8
    for (int j = 0; j < 32; ++j) kk += q2[j] * zred[256 + j];
    kls[tid] = kk;
  }

  f32x4 acc1[2][2];
#pragma unroll
  for (int a = 0; a < 2; ++a)
#pragma unroll
    for (int b = 0; b < 2; ++b) acc1[a][b] = (f32x4){0.f, 0.f, 0.f, 0.f};

#pragma unroll
  for (int ph = 0; ph < 2; ++ph) {
#pragma unroll
    for (int k = 0; k < 8; ++k) {
      int f = k * 256 + tid, c = f >> 5, n4 = f & 31;
      int u = n4 ^ ((c >> 2) & 6);
      uint4 pk;
      pk.x = pack_hilo(xr[k].x); pk.y = pack_hilo(xr[k].y);
      pk.z = pack_hilo(xr[k].z); pk.w = pack_hilo(xr[k].w);
      *(uint4*)&xs[c * 128 + u * 4] = pk;
    }
    __syncthreads();
    if (ph == 0) {
#pragma unroll
      for (int k = 0; k < 8; ++k) {
        int f = k * 256 + tid, c = f >> 5, n4 = f & 31;
        xr[k] = *(const float4*)(xblk + (size_t)(64 + c) * CHUNKF + n4 * 4);
      }
    }
#pragma unroll
    for (int kl = 0; kl < 2; ++kl) {
#pragma unroll
      for (int nt = 0; nt < 2; ++nt) {
        const int n = wv * 32 + nt * 16 + ln;
        const int base = (kl * 32 + g * 8) * 128;
        const int u = ((n >> 2) ^ (((kl * 32 + g * 8) >> 2) & 6)) * 4 + (n & 3);
        uint q0 = xs[base + 0 * 128 + u], q1 = xs[base + 1 * 128 + u];
        uint q2 = xs[base + 2 * 128 + u], q3 = xs[base + 3 * 128 + u];
        uint q4 = xs[base + 4 * 128 + u], q5 = xs[base + 5 * 128 + u];
        uint q6 = xs[base + 6 * 128 + u], q7 = xs[base + 7 * 128 + u];
        uint4 H, L;
        H.x = (q0 & 0xffffu) | (q1 << 16);  H.y = (q2 & 0xffffu) | (q3 << 16);
        H.z = (q4 & 0xffffu) | (q5 << 16);  H.w = (q6 & 0xffffu) | (q7 << 16);
        L.x = (q0 >> 16) | (q1 & 0xffff0000u); L.y = (q2 >> 16) | (q3 & 0xffff0000u);
        L.z = (q4 >> 16) | (q5 & 0xffff0000u); L.w = (q6 >> 16) | (q7 & 0xffff0000u);
        s16x8 Bh = __builtin_bit_cast(s16x8, H);
        s16x8 Bl = __builtin_bit_cast(s16x8, L);
#pragma unroll
        for (int jt = 0; jt < 2; ++jt) {
          acc1[jt][nt] = __builtin_amdgcn_mfma_f32_16x16x32_bf16(A1[jt][ph * 2 + kl], Bh, acc1[jt][nt], 0, 0, 0);
          acc1[jt][nt] = __builtin_amdgcn_mfma_f32_16x16x32_bf16(A1[jt][ph * 2 + kl], Bl, acc1[jt][nt], 0, 0, 0);
        }
      }
    }
    __syncthreads();
  }

  uint* zw = xs + wv * 1024;
#pragma unroll
  for (int jt = 0; jt < 2; ++jt)
#pragma unroll
    for (int nt = 0; nt < 2; ++nt) {
      int n = nt * 16 + ln;
      int u = (jt * 4 + g) ^ (n & 7);
      uint4 pk;
      pk.x = pack_hilo(acc1[jt][nt][0]);
      pk.y = pack_hilo(acc1[jt][nt][1]);
      pk.z = pack_hilo(acc1[jt][nt][2]);
      pk.w = pack_hilo(acc1[jt][nt][3]);
      *(uint4*)&zw[n * 32 + u * 4] = pk;
    }

  s16x8 Ah[2], Al[2];
#pragma unroll
  for (int mt = 0; mt < 2; ++mt) {
    int n = mt * 16 + ln;
    int u0 = (2 * g) ^ (n & 7);
    int u1 = (2 * g + 1) ^ (n & 7);
    uint4 qa = *(const uint4*)&zw[n * 32 + u0 * 4];
    uint4 qb = *(const uint4*)&zw[n * 32 + u1 * 4];
    uint4 H, L;
    H.x = (qa.x & 0xffffu) | (qa.y << 16);  H.y = (qa.z & 0xffffu) | (qa.w << 16);
    H.z = (qb.x & 0xffffu) | (qb.y << 16);  H.w = (qb.z & 0xffffu) | (qb.w << 16);
    L.x = (qa.x >> 16) | (qa.y & 0xffff0000u); L.y = (qa.z >> 16) | (qa.w & 0xffff0000u);
    L.z = (qb.x >> 16) | (qb.y & 0xffff0000u); L.w = (qb.z >> 16) | (qb.w & 0xffff0000u);
    Ah[mt] = __builtin_bit_cast(s16x8, H);
    Al[mt] = __builtin_bit_cast(s16x8, L);
  }

  const size_t outbase = (size_t)nb * CIN * CHUNKF + (size_t)(hw0 + wv) * 32;
#pragma unroll 1
  for (int h = 0; h < 2; ++h) {
    s16x8 B2[4];
#pragma unroll
    for (int q = 0; q < 4; ++q)
      B2[q] = *(const s16x8*)(qw2bf + ((h * 4 + q) * 16 + ln) * 32 + g * 8);
    f32x4 acc2[4][2];
#pragma unroll
    for (int a = 0; a < 4; ++a)
#pragma unroll
      for (int b = 0; b < 2; ++b) acc2[a][b] = (f32x4){0.f, 0.f, 0.f, 0.f};
#pragma unroll
    for (int mt = 0; mt < 2; ++mt)
#pragma unroll
      for (int q = 0; q < 4; ++q) {
        acc2[q][mt] = __builtin_amdgcn_mfma_f32_16x16x32_bf16(Ah[mt], B2[q], acc2[q][mt], 0, 0, 0);
        acc2[q][mt] = __builtin_amdgcn_mfma_f32_16x16x32_bf16(Al[mt], B2[q], acc2[q][mt], 0, 0, 0);
      }
#pragma unroll
    for (int q = 0; q < 4; ++q) {
      const int nt = h * 4 + q;
      float c0[2], c1[2], c2[2], c3[2], base[2], Qi0 = 0.f;
#pragma unroll
      for (int mt = 0; mt < 2; ++mt) {
        c0[mt] = acc2[q][mt][0];
        c1[mt] = c0[mt] + acc2[q][mt][1];
        c2[mt] = c1[mt] + acc2[q][mt][2];
        c3[mt] = c2[mt] + acc2[q][mt][3];
        float Qi = c3[mt];
        float t1 = __shfl_up(Qi, 16); if (g >= 1) Qi += t1;
        float t2 = __shfl_up(Qi, 32); if (g >= 2) Qi += t2;
        base[mt] = Qi - c3[mt];
        if (mt == 0) Qi0 = Qi;
      }
      float S0tot = __shfl(Qi0, 48 + ln);
      base[1] += S0tot;
      const float kpp = kls[nt * 16 + ln];
      float* op = out + outbase + (size_t)(nt * 16 + ln) * CHUNKF;
#pragma unroll
      for (int mt = 0; mt < 2; ++mt) {
        float Bv = base[mt] - kpp;
        float prev = fminf(fmaxf(Bv, -6.f), 6.f);
        if (mt == 0 && g == 0) prev = 0.f;
        float A0 = fminf(fmaxf(Bv + c0[mt], -6.f), 6.f);
        float A1v = fminf(fmaxf(Bv + c1[mt], -6.f), 6.f);
        float A2v = fminf(fmaxf(Bv + c2[mt], -6.f), 6.f);
        float A3v = fminf(fmaxf(Bv + c3[mt], -6.f), 6.f);
        *(float4*)(op + mt * 16 + g * 4) =
            make_float4(A0 - prev, A1v - A0, A2v - A1v, A3v - A2v);
      }
    }
  }
}

// ======================= COOPERATIVE (single-pass) =======================
// 512 blocks x 256 thr (>= 2 blocks/CU guaranteed: VGPR<=256, LDS ~34KB).
// Block owns 8 hw positions. Pre-sync: mean partials (+wnorm on blocks<160).
// grid.sync. Post-sync: kappa, then r12 MFMA pipeline twice (4 pos each),
// x re-read from L3.
__global__ __launch_bounds__(256, 2) void fused_all(
    const float* __restrict__ x,
    const float* __restrict__ v1, const float* __restrict__ g1,
    const float* __restrict__ v2, const float* __restrict__ g2,
    float* __restrict__ ws, float* __restrict__ out) {
  __shared__ uint xs[8192];
  __shared__ float mls[128];
  __shared__ float zred[256];
  __shared__ float zsm[32];
  __shared__ float kls[128];
  __shared__ double wpart[4];

  const int tid = threadIdx.x;
  const int bid = blockIdx.x;
  const int nb  = bid >> 7;
  const int hw8 = (bid & 127) * 8;
  float* msumP = ws + 8192;

  // ---- pre-sync: mean partials. Wave w covers one full c-row per k.
  {
    const int l63 = tid & 63, wvp = tid >> 6;
    const int t0 = (4 * l63) & 31;
    const float wt0 = (float)(32 - t0), wt1 = (float)(31 - t0);
    const float wt2 = (float)(30 - t0), wt3 = (float)(29 - t0);
    const int slot = bid & 31;
    const float* xsl = x + (size_t)nb * CIN * CHUNKF + (size_t)hw8 * 32 + l63 * 4;
#pragma unroll 4
    for (int k = 0; k < 32; ++k) {
      int c = k * 4 + wvp;
      float4 v = *(const float4*)(xsl + (size_t)c * CHUNKF);
      float pv = v.x * wt0 + v.y * wt1 + v.z * wt2 + v.w * wt3;
      pv += __shfl_down(pv, 32);
      pv += __shfl_down(pv, 16);
      pv += __shfl_down(pv, 8);
      pv += __shfl_down(pv, 4);
      pv += __shfl_down(pv, 2);
      pv += __shfl_down(pv, 1);
      if (l63 == 0) atomicAdd(&msumP[slot * 128 + c], pv);
    }
  }

  // ---- pre-sync: wnorm duty (blocks 0..159)
  if (bid < 160) {
    bool first = (bid < 32);
    int row = first ? bid : bid - 32;
    int len = first ? 128 : 32;
    const float* v = first ? v1 : v2;
    const float* g = first ? g1 : g2;
    double val = 0.0;
    if (tid < len) { double t = (double)v[row * len + tid]; val = t * t; }
    for (int off = 32; off >= 1; off >>= 1) val += __shfl_down(val, off);
    if ((tid & 63) == 0) wpart[tid >> 6] = val;
    __syncthreads();
    double norm = sqrt(wpart[0] + wpart[1]);
    if (tid < len) {
      double w = (double)g[row] * (double)v[row * len + tid] / norm;
      double qd = rint(w * 32.0) * 0.03125;
      qd = fmin(fmax(qd, -2.0), 1.984375);
      float qf = (float)qd;
      ushort bf = (ushort)(__float_as_uint(qf) >> 16);
      if (first) {
        ws[row * 128 + tid] = qf;
        ((ushort*)(ws + 12544))[row * 128 + tid] = bf;
      } else {
        ws[4096 + row * 32 + tid] = qf;
        ((ushort*)(ws + 14592))[row * 32 + tid] = bf;
      }
    }
  }

  cg::this_grid().sync();

  // ---- post-sync
  const ushort* qw1bf = (const ushort*)(ws + 12544);
  const ushort* qw2bf = (const ushort*)(ws + 14592);
  const int wv = tid >> 6;
  const int l  = tid & 63;
  const int g  = l >> 4;
  const int ln = l & 15;

  s16x8 A1[2][4];
#pragma unroll
  for (int jt = 0; jt < 2; ++jt)
#pragma unroll
    for (int ks = 0; ks < 4; ++ks)
      A1[jt][ks] = *(const s16x8*)(qw1bf + (jt * 16 + ln) * 128 + ks * 32 + g * 8);

  // issue grp0 ph0 loads (L3-hot)
  float4 xr[8];
  {
    const float* xg = x + (size_t)nb * CIN * CHUNKF + (size_t)hw8 * 32;
#pragma unroll
    for (int k = 0; k < 8; ++k) {
      int f = k * 256 + tid, c = f >> 5, n4 = f & 31;
      xr[k] = *(const float4*)(xg + (size_t)c * CHUNKF + n4 * 4);
    }
  }

  if (tid < 128) {
    float m = 0.f;
#pragma unroll
    for (int p = 0; p < 32; ++p) m += msumP[p * 128 + tid];
    mls[tid] = m;
  }
  __syncthreads();
  {
    int j = tid & 31, grp8 = tid >> 5;
    const float* qr = ws + j * 128 + grp8 * 16;
    float pp = 0.f;
#pragma unroll
    for (int cc = 0; cc < 16; ++cc) pp += qr[cc] * mls[grp8 * 16 + cc];
    zred[j * 8 + grp8] = pp;
  }
  __syncthreads();
  if (tid < 32) {
    float t = 0.f;
#pragma unroll
    for (int gg = 0; gg < 8; ++gg) t += zred[tid * 8 + gg];
    zsm[tid] = t * (1.0f / 131072.0f);
  }
  __syncthreads();
  if (tid < 128) {
    const float* q2p = ws + 4096 + tid * 32;
    float kk = 0.f;
#pragma unroll 8
    for (int j = 0; j < 32; ++j) kk += q2p[j] * zsm[j];
    kls[tid] = kk;
  }

#pragma unroll 1
  for (int grp = 0; grp < 2; ++grp) {
    const int hw0 = hw8 + grp * 4;
    const float* xg = x + (size_t)nb * CIN * CHUNKF + (size_t)hw0 * 32;

    f32x4 acc1[2][2];
#pragma unroll
    for (int a = 0; a < 2; ++a)
#pragma unroll
      for (int b = 0; b < 2; ++b) acc1[a][b] = (f32x4){0.f, 0.f, 0.f, 0.f};

    __syncthreads();   // B0: kls ready (grp0) / zw reads done (grp1)

#pragma unroll
    for (int ph = 0; ph < 2; ++ph) {
#pragma unroll
      for (int k = 0; k < 8; ++k) {
        int f = k * 256 + tid, c = f >> 5, n4 = f & 31;
        int u = n4 ^ ((c >> 2) & 6);
        uint4 pk;
        pk.x = pack_hilo(xr[k].x); pk.y = pack_hilo(xr[k].y);
        pk.z = pack_hilo(xr[k].z); pk.w = pack_hilo(xr[k].w);
        *(uint4*)&xs[c * 128 + u * 4] = pk;
      }
      __syncthreads();
      if (ph == 0) {
#pragma unroll
        for (int k = 0; k < 8; ++k) {
          int f = k * 256 + tid, c = f >> 5, n4 = f & 31;
          xr[k] = *(const float4*)(xg + (size_t)(64 + c) * CHUNKF + n4 * 4);
        }
      }
#pragma unroll
      for (int kl = 0; kl < 2; ++kl) {
#pragma unroll
        for (int nt = 0; nt < 2; ++nt) {
          const int n = wv * 32 + nt * 16 + ln;
          const int base = (kl * 32 + g * 8) * 128;
          const int u = ((n >> 2) ^ (((kl * 32 + g * 8) >> 2) & 6)) * 4 + (n & 3);
          uint q0 = xs[base + 0 * 128 + u], q1 = xs[base + 1 * 128 + u];
          uint q2 = xs[base + 2 * 128 + u], q3 = xs[base + 3 * 128 + u];
          uint q4 = xs[base + 4 * 128 + u], q5 = xs[base + 5 * 128 + u];
          uint q6 = xs[base + 6 * 128 + u], q7 = xs[base + 7 * 128 + u];
          uint4 H, L;
          H.x = (q0 & 0xffffu) | (q1 << 16);  H.y = (q2 & 0xffffu) | (q3 << 16);
          H.z = (q4 & 0xffffu) | (q5 << 16);  H.w = (q6 & 0xffffu) | (q7 << 16);
          L.x = (q0 >> 16) | (q1 & 0xffff0000u); L.y = (q2 >> 16) | (q3 & 0xffff0000u);
          L.z = (q4 >> 16) | (q5 & 0xffff0000u); L.w = (q6 >> 16) | (q7 & 0xffff0000u);
          s16x8 Bh = __builtin_bit_cast(s16x8, H);
          s16x8 Bl = __builtin_bit_cast(s16x8, L);
#pragma unroll
          for (int jt = 0; jt < 2; ++jt) {
            acc1[jt][nt] = __builtin_amdgcn_mfma_f32_16x16x32_bf16(A1[jt][ph * 2 + kl], Bh, acc1[jt][nt], 0, 0, 0);
            acc1[jt][nt] = __builtin_amdgcn_mfma_f32_16x16x32_bf16(A1[jt][ph * 2 + kl], Bl, acc1[jt][nt], 0, 0, 0);
          }
        }
      }
      __syncthreads();
    }

    uint* zw = xs + wv * 1024;
#pragma unroll
    for (int jt = 0; jt < 2; ++jt)
#pragma unroll
      for (int nt = 0; nt < 2; ++nt) {
        int n = nt * 16 + ln;
        int u = (jt * 4 + g) ^ (n & 7);
        uint4 pk;
        pk.x = pack_hilo(acc1[jt][nt][0]);
        pk.y = pack_hilo(acc1[jt][nt][1]);
        pk.z = pack_hilo(acc1[jt][nt][2]);
        pk.w = pack_hilo(acc1[jt][nt][3]);
        *(uint4*)&zw[n * 32 + u * 4] = pk;
      }

    s16x8 Ah[2], Al[2];
#pragma unroll
    for (int mt = 0; mt < 2; ++mt) {
      int n = mt * 16 + ln;
      int u0 = (2 * g) ^ (n & 7);
      int u1 = (2 * g + 1) ^ (n & 7);
      uint4 qa = *(const uint4*)&zw[n * 32 + u0 * 4];
      uint4 qb = *(const uint4*)&zw[n * 32 + u1 * 4];
      uint4 H, L;
      H.x = (qa.x & 0xffffu) | (qa.y << 16);  H.y = (qa.z & 0xffffu) | (qa.w << 16);
      H.z = (qb.x & 0xffffu) | (qb.y << 16);  H.w = (qb.z & 0xffffu) | (qb.w << 16);
      L.x = (qa.x >> 16) | (qa.y & 0xffff0000u); L.y = (qa.z >> 16) | (qa.w & 0xffff0000u);
      L.z = (qb.x >> 16) | (qb.y & 0xffff0000u); L.w = (qb.z >> 16) | (qb.w & 0xffff0000u);
      Ah[mt] = __builtin_bit_cast(s16x8, H);
      Al[mt] = __builtin_bit_cast(s16x8, L);
    }

    if (grp == 0) {   // issue grp1 ph0 loads; epilogue below covers latency
      const float* xg1 = x + (size_t)nb * CIN * CHUNKF + (size_t)(hw8 + 4) * 32;
#pragma unroll
      for (int k = 0; k < 8; ++k) {
        int f = k * 256 + tid, c = f >> 5, n4 = f & 31;
        xr[k] = *(const float4*)(xg1 + (size_t)c * CHUNKF + n4 * 4);
      }
    }

    const size_t outbase = (size_t)nb * CIN * CHUNKF + (size_t)(hw0 + wv) * 32;
#pragma unroll 1
    for (int h = 0; h < 2; ++h) {
      s16x8 B2[4];
#pragma unroll
      for (int q = 0; q < 4; ++q)
        B2[q] = *(const s16x8*)(qw2bf + ((h * 4 + q) * 16 + ln) * 32 + g * 8);
      f32x4 acc2[4][2];
#pragma unroll
      for (int a = 0; a < 4; ++a)
#pragma unroll
        for (int b = 0; b < 2; ++b) acc2[a][b] = (f32x4){0.f, 0.f, 0.f, 0.f};
#pragma unroll
      for (int mt = 0; mt < 2; ++mt)
#pragma unroll
        for (int q = 0; q < 4; ++q) {
          acc2[q][mt] = __builtin_amdgcn_mfma_f32_16x16x32_bf16(Ah[mt], B2[q], acc2[q][mt], 0, 0, 0);
          acc2[q][mt] = __builtin_amdgcn_mfma_f32_16x16x32_bf16(Al[mt], B2[q], acc2[q][mt], 0, 0, 0);
        }
#pragma unroll
      for (int q = 0; q < 4; ++q) {
        const int nt = h * 4 + q;
        float c0[2], c1[2], c2[2], c3[2], base[2], Qi0 = 0.f;
#pragma unroll
        for (int mt = 0; mt < 2; ++mt) {
          c0[mt] = acc2[q][mt][0];
          c1[mt] = c0[mt] + acc2[q][mt][1];
          c2[mt] = c1[mt] + acc2[q][mt][2];
          c3[mt] = c2[mt] + acc2[q][mt][3];
          float Qi = c3[mt];
          float t1 = __shfl_up(Qi, 16); if (g >= 1) Qi += t1;
          float t2 = __shfl_up(Qi, 32); if (g >= 2) Qi += t2;
          base[mt] = Qi - c3[mt];
          if (mt == 0) Qi0 = Qi;
        }
        float S0tot = __shfl(Qi0, 48 + ln);
        base[1] += S0tot;
        const float kpp = kls[nt * 16 + ln];
        float* op = out + outbase + (size_t)(nt * 16 + ln) * CHUNKF;
#pragma unroll
        for (int mt = 0; mt < 2; ++mt) {
          float Bv = base[mt] - kpp;
          float prev = fminf(fmaxf(Bv, -6.f), 6.f);
          if (mt == 0 && g == 0) prev = 0.f;
          float A0 = fminf(fmaxf(Bv + c0[mt], -6.f), 6.f);
          float A1v = fminf(fmaxf(Bv + c1[mt], -6.f), 6.f);
          float A2v = fminf(fmaxf(Bv + c2[mt], -6.f), 6.f);
          float A3v = fminf(fmaxf(Bv + c3[mt], -6.f), 6.f);
          *(float4*)(op + mt * 16 + g * 4) =
              make_float4(A0 - prev, A1v - A0, A2v - A1v, A3v - A2v);
        }
      }
    }
  }
}

extern "C" void kernel_launch(void* const* d_in, const int* in_sizes, int n_in,
                              void* d_out, int out_size, void* d_ws, size_t ws_size,
                              hipStream_t stream) {
  const float* x  = (const float*)d_in[0];
  const float* v1 = (const float*)d_in[1];
  const float* g1 = (const float*)d_in[2];
  const float* v2 = (const float*)d_in[3];
  const float* g2 = (const float*)d_in[4];
  float* ws  = (float*)d_ws;
  float* out = (float*)d_out;

  hipMemsetAsync(ws + 8192, 0, 4096 * sizeof(float), stream);

  // capture-safe host-side viability checks (no stream ops)
  int dev = 0, coop = 0, occ = 0;
  hipGetDevice(&dev);
  hipDeviceGetAttribute(&coop, hipDeviceAttributeCooperativeLaunch, dev);
  hipOccupancyMaxActiveBlocksPerMultiprocessor(&occ, fused_all, 256, 0);

  if (coop && occ >= 2) {
    void* args[] = { (void*)&x, (void*)&v1, (void*)&g1, (void*)&v2, (void*)&g2,
                     (void*)&ws, (void*)&out };
    hipError_t e = hipLaunchCooperativeKernel((const void*)fused_all, dim3(512),
                                              dim3(256), args, 0, stream);
    if (e == hipSuccess) return;
  }

  // fallback: r12-proven two-kernel path
  wnorm_mean_kernel<<<2208, 256, 0, stream>>>(x, v1, g1, v2, g2, ws);
  fused_kernel<<<1024, 256, 0, stream>>>(x, ws, out);
}

// Round 15
// 48.761 us; speedup vs baseline: 1.3407x; 1.0105x over previous
//
#include <hip/hip_runtime.h>

#define CIN  128
#define CHUNKF 32768       // HW*T floats per (n, channel)

typedef float f32x4 __attribute__((ext_vector_type(4)));
typedef short s16x8 __attribute__((ext_vector_type(8)));

// ws float layout (main path):
// [0,4096)       qw1 f32 [32 o1][128 c]
// [4096,8192)    qw2 f32 [128 o2][32 j]
// [8192,12288)   msumP [32 slot][128 c] (atomic partials)
// [12288]        done counter (uint)
// [12544,14592)  qw1bf ushort[32][128]
// [14592,16640)  qw2bf ushort[128][32]
// Fallback path (r12): msum at 8192(128), qw1bf at 8448, qw2bf at 10496.

__device__ __forceinline__ uint pack_hilo(float f) {
  uint b = __float_as_uint(f);
  uint hi = b & 0xffff0000u;
  float lo = f - __uint_as_float(hi);
  return (hi >> 16) | (__float_as_uint(lo) & 0xffff0000u);
}

// ===================== MAIN PATH =====================
// weights + zero msumP/counter. 160 blocks x 128 thr.
__global__ __launch_bounds__(128) void wnorm_init(
    const float* __restrict__ v1, const float* __restrict__ g1,
    const float* __restrict__ v2, const float* __restrict__ g2,
    float* __restrict__ ws) {
  int b = blockIdx.x, tid = threadIdx.x;
  if (b < 32) ws[8192 + b * 128 + tid] = 0.f;            // msumP
  if (b == 32 && tid == 0) *(uint*)(ws + 12288) = 0u;    // done counter
  bool first = (b < 32);
  int row = first ? b : b - 32;
  int len = first ? 128 : 32;
  const float* v = first ? v1 : v2;
  const float* g = first ? g1 : g2;

  double val = 0.0;
  if (tid < len) { double t = (double)v[row * len + tid]; val = t * t; }
  for (int off = 32; off >= 1; off >>= 1) val += __shfl_down(val, off);
  __shared__ double partial[2];
  if ((tid & 63) == 0) partial[tid >> 6] = val;
  __syncthreads();
  double norm = sqrt(partial[0] + partial[1]);
  if (tid < len) {
    double w = (double)g[row] * (double)v[row * len + tid] / norm;
    double qd = rint(w * 32.0) * 0.03125;        // step 2/64, round-half-even
    qd = fmin(fmax(qd, -2.0), 1.984375);
    float qf = (float)qd;                        // bf16-exact
    ushort bf = (ushort)(__float_as_uint(qf) >> 16);
    if (first) {
      ws[row * 128 + tid] = qf;                            // qw1 f32
      ((ushort*)(ws + 12544))[row * 128 + tid] = bf;       // qw1bf
    } else {
      ws[4096 + row * 32 + tid] = qf;                      // qw2 f32
      ((ushort*)(ws + 14592))[row * 32 + tid] = bf;        // qw2bf
    }
  }
}

// Single main kernel: mean-deposit -> MFMA pipeline -> spin+kappa -> epilogue.
// 1024 blocks x 256 thr, 4 blocks/CU (all co-resident; host-gated).
__global__ __launch_bounds__(256, 4) void fused_main(
    const float* __restrict__ x, float* __restrict__ ws,
    float* __restrict__ out) {
  const ushort* qw1bf = (const ushort*)(ws + 12544);
  const ushort* qw2bf = (const ushort*)(ws + 14592);

  __shared__ uint xs[8192];     // 32 KB; z overlays after barrier
  __shared__ float mls[128];
  __shared__ float zred[288];
  __shared__ float kls[128];

  const int tid = threadIdx.x;
  const int wv = tid >> 6;
  const int l  = tid & 63;
  const int g  = l >> 4;
  const int ln = l & 15;

  const int nb  = blockIdx.x >> 8;
  const int hw0 = (blockIdx.x & 255) * 4;
  const float* xblk = x + (size_t)nb * CIN * CHUNKF + (size_t)hw0 * 32;
  float* msumP = ws + 8192;

  // ---- phase A: mean partials over own slice (HBM read, also warms L1/L2)
  {
    const int l31 = tid & 31;
    const int t0 = (l31 & 7) * 4;
    const float wt0 = (float)(32 - t0), wt1 = (float)(31 - t0);
    const float wt2 = (float)(30 - t0), wt3 = (float)(29 - t0);
    const int slot = blockIdx.x & 31;
#pragma unroll 4
    for (int k = 0; k < 16; ++k) {
      int c = k * 8 + (tid >> 5);
      float4 v = *(const float4*)(xblk + (size_t)c * CHUNKF + l31 * 4);
      float pv = v.x * wt0 + v.y * wt1 + v.z * wt2 + v.w * wt3;
      pv += __shfl_down(pv, 16, 32);
      pv += __shfl_down(pv, 8, 32);
      pv += __shfl_down(pv, 4, 32);
      pv += __shfl_down(pv, 2, 32);
      pv += __shfl_down(pv, 1, 32);
      if (l31 == 0) atomicAdd(&msumP[slot * 128 + c], pv);
    }
  }
  __threadfence();               // my atomics visible device-wide
  __syncthreads();               // whole block done depositing
  if (tid == 0) atomicAdd((uint*)(ws + 12288), 1u);

  // ---- phase B: MFMA pipeline (x loads now L1/L2-hot)
  float4 xr[8];
#pragma unroll
  for (int k = 0; k < 8; ++k) {
    int f = k * 256 + tid, c = f >> 5, n4 = f & 31;
    xr[k] = *(const float4*)(xblk + (size_t)c * CHUNKF + n4 * 4);
  }

  s16x8 A1[2][4];
#pragma unroll
  for (int jt = 0; jt < 2; ++jt)
#pragma unroll
    for (int ks = 0; ks < 4; ++ks)
      A1[jt][ks] = *(const s16x8*)(qw1bf + (jt * 16 + ln) * 128 + ks * 32 + g * 8);

  f32x4 acc1[2][2];
#pragma unroll
  for (int a = 0; a < 2; ++a)
#pragma unroll
    for (int b = 0; b < 2; ++b) acc1[a][b] = (f32x4){0.f, 0.f, 0.f, 0.f};

#pragma unroll
  for (int ph = 0; ph < 2; ++ph) {
#pragma unroll
    for (int k = 0; k < 8; ++k) {
      int f = k * 256 + tid, c = f >> 5, n4 = f & 31;
      int u = n4 ^ ((c >> 2) & 6);
      uint4 pk;
      pk.x = pack_hilo(xr[k].x); pk.y = pack_hilo(xr[k].y);
      pk.z = pack_hilo(xr[k].z); pk.w = pack_hilo(xr[k].w);
      *(uint4*)&xs[c * 128 + u * 4] = pk;
    }
    __syncthreads();
    if (ph == 0) {
#pragma unroll
      for (int k = 0; k < 8; ++k) {
        int f = k * 256 + tid, c = f >> 5, n4 = f & 31;
        xr[k] = *(const float4*)(xblk + (size_t)(64 + c) * CHUNKF + n4 * 4);
      }
    }
#pragma unroll
    for (int kl = 0; kl < 2; ++kl) {
#pragma unroll
      for (int nt = 0; nt < 2; ++nt) {
        const int n = wv * 32 + nt * 16 + ln;
        const int base = (kl * 32 + g * 8) * 128;
        const int u = ((n >> 2) ^ (((kl * 32 + g * 8) >> 2) & 6)) * 4 + (n & 3);
        uint q0 = xs[base + 0 * 128 + u], q1 = xs[base + 1 * 128 + u];
        uint q2 = xs[base + 2 * 128 + u], q3 = xs[base + 3 * 128 + u];
        uint q4 = xs[base + 4 * 128 + u], q5 = xs[base + 5 * 128 + u];
        uint q6 = xs[base + 6 * 128 + u], q7 = xs[base + 7 * 128 + u];
        uint4 H, L;
        H.x = (q0 & 0xffffu) | (q1 << 16);  H.y = (q2 & 0xffffu) | (q3 << 16);
        H.z = (q4 & 0xffffu) | (q5 << 16);  H.w = (q6 & 0xffffu) | (q7 << 16);
        L.x = (q0 >> 16) | (q1 & 0xffff0000u); L.y = (q2 >> 16) | (q3 & 0xffff0000u);
        L.z = (q4 >> 16) | (q5 & 0xffff0000u); L.w = (q6 >> 16) | (q7 & 0xffff0000u);
        s16x8 Bh = __builtin_bit_cast(s16x8, H);
        s16x8 Bl = __builtin_bit_cast(s16x8, L);
#pragma unroll
        for (int jt = 0; jt < 2; ++jt) {
          acc1[jt][nt] = __builtin_amdgcn_mfma_f32_16x16x32_bf16(A1[jt][ph * 2 + kl], Bh, acc1[jt][nt], 0, 0, 0);
          acc1[jt][nt] = __builtin_amdgcn_mfma_f32_16x16x32_bf16(A1[jt][ph * 2 + kl], Bl, acc1[jt][nt], 0, 0, 0);
        }
      }
    }
    __syncthreads();
  }

  // ---- z -> wave-private slab overlaying xs
  uint* zw = xs + wv * 1024;
#pragma unroll
  for (int jt = 0; jt < 2; ++jt)
#pragma unroll
    for (int nt = 0; nt < 2; ++nt) {
      int n = nt * 16 + ln;
      int u = (jt * 4 + g) ^ (n & 7);
      uint4 pk;
      pk.x = pack_hilo(acc1[jt][nt][0]);
      pk.y = pack_hilo(acc1[jt][nt][1]);
      pk.z = pack_hilo(acc1[jt][nt][2]);
      pk.w = pack_hilo(acc1[jt][nt][3]);
      *(uint4*)&zw[n * 32 + u * 4] = pk;
    }

  s16x8 Ah[2], Al[2];
#pragma unroll
  for (int mt = 0; mt < 2; ++mt) {
    int n = mt * 16 + ln;
    int u0 = (2 * g) ^ (n & 7);
    int u1 = (2 * g + 1) ^ (n & 7);
    uint4 qa = *(const uint4*)&zw[n * 32 + u0 * 4];
    uint4 qb = *(const uint4*)&zw[n * 32 + u1 * 4];
    uint4 H, L;
    H.x = (qa.x & 0xffffu) | (qa.y << 16);  H.y = (qa.z & 0xffffu) | (qa.w << 16);
    H.z = (qb.x & 0xffffu) | (qb.y << 16);  H.w = (qb.z & 0xffffu) | (qb.w << 16);
    L.x = (qa.x >> 16) | (qa.y & 0xffff0000u); L.y = (qa.z >> 16) | (qa.w & 0xffff0000u);
    L.z = (qb.x >> 16) | (qb.y & 0xffff0000u); L.w = (qb.z >> 16) | (qb.w & 0xffff0000u);
    Ah[mt] = __builtin_bit_cast(s16x8, H);
    Al[mt] = __builtin_bit_cast(s16x8, L);
  }

  // ---- phase C: wait for all mean deposits (already done in practice), kappa
  if (tid == 0) {
    const uint* dc = (const uint*)(ws + 12288);
    int guard = 0;
    while (__hip_atomic_load(dc, __ATOMIC_ACQUIRE, __HIP_MEMORY_SCOPE_AGENT) < 1024u
           && ++guard < 10000000) { }
  }
  __syncthreads();
  __threadfence();
  if (tid < 128) {
    float m = 0.f;
#pragma unroll
    for (int p = 0; p < 32; ++p)
      m += __hip_atomic_load(&msumP[p * 128 + tid], __ATOMIC_RELAXED,
                             __HIP_MEMORY_SCOPE_AGENT);
    mls[tid] = m * (1.0f / 131072.0f);
  }
  __syncthreads();
  {
    int j = tid & 31, grp = tid >> 5;
    const float* qr = ws + j * 128 + grp * 16;
    float pp = 0.f;
#pragma unroll
    for (int cc = 0; cc < 16; ++cc) pp += qr[cc] * mls[grp * 16 + cc];
    zred[j * 8 + grp] = pp;
  }
  __syncthreads();
  if (tid < 32) {
    float t = 0.f;
#pragma unroll
    for (int gg = 0; gg < 8; ++gg) t += zred[tid * 8 + gg];
    zred[256 + tid] = t;
  }
  __syncthreads();
  if (tid < 128) {
    const float* q2 = ws + 4096 + tid * 32;
    float kk = 0.f;
#pragma unroll 8
    for (int j = 0; j < 32; ++j) kk += q2[j] * zred[256 + j];
    kls[tid] = kk;
  }
  __syncthreads();

  // ---- stage 2 + epilogue (r12-proven)
  const size_t outbase = (size_t)nb * CIN * CHUNKF + (size_t)(hw0 + wv) * 32;
#pragma unroll 1
  for (int h = 0; h < 2; ++h) {
    s16x8 B2[4];
#pragma unroll
    for (int q = 0; q < 4; ++q)
      B2[q] = *(const s16x8*)(qw2bf + ((h * 4 + q) * 16 + ln) * 32 + g * 8);
    f32x4 acc2[4][2];
#pragma unroll
    for (int a = 0; a < 4; ++a)
#pragma unroll
      for (int b = 0; b < 2; ++b) acc2[a][b] = (f32x4){0.f, 0.f, 0.f, 0.f};
#pragma unroll
    for (int mt = 0; mt < 2; ++mt)
#pragma unroll
      for (int q = 0; q < 4; ++q) {
        acc2[q][mt] = __builtin_amdgcn_mfma_f32_16x16x32_bf16(Ah[mt], B2[q], acc2[q][mt], 0, 0, 0);
        acc2[q][mt] = __builtin_amdgcn_mfma_f32_16x16x32_bf16(Al[mt], B2[q], acc2[q][mt], 0, 0, 0);
      }
#pragma unroll
    for (int q = 0; q < 4; ++q) {
      const int nt = h * 4 + q;
      float c0[2], c1[2], c2[2], c3[2], base[2], Qi0 = 0.f;
#pragma unroll
      for (int mt = 0; mt < 2; ++mt) {
        c0[mt] = acc2[q][mt][0];
        c1[mt] = c0[mt] + acc2[q][mt][1];
        c2[mt] = c1[mt] + acc2[q][mt][2];
        c3[mt] = c2[mt] + acc2[q][mt][3];
        float Qi = c3[mt];
        float t1 = __shfl_up(Qi, 16); if (g >= 1) Qi += t1;
        float t2 = __shfl_up(Qi, 32); if (g >= 2) Qi += t2;
        base[mt] = Qi - c3[mt];
        if (mt == 0) Qi0 = Qi;
      }
      float S0tot = __shfl(Qi0, 48 + ln);
      base[1] += S0tot;
      const float kpp = kls[nt * 16 + ln];
      float* op = out + outbase + (size_t)(nt * 16 + ln) * CHUNKF;
#pragma unroll
      for (int mt = 0; mt < 2; ++mt) {
        float Bv = base[mt] - kpp;
        float prev = fminf(fmaxf(Bv, -6.f), 6.f);
        if (mt == 0 && g == 0) prev = 0.f;
        float A0 = fminf(fmaxf(Bv + c0[mt], -6.f), 6.f);
        float A1v = fminf(fmaxf(Bv + c1[mt], -6.f), 6.f);
        float A2v = fminf(fmaxf(Bv + c2[mt], -6.f), 6.f);
        float A3v = fminf(fmaxf(Bv + c3[mt], -6.f), 6.f);
        *(float4*)(op + mt * 16 + g * 4) =
            make_float4(A0 - prev, A1v - A0, A2v - A1v, A3v - A2v);
      }
    }
  }
}

// ===================== FALLBACK (r12-proven, verbatim) =====================
__global__ __launch_bounds__(256) void wnorm_mean_kernel(
    const float* __restrict__ x,
    const float* __restrict__ v1, const float* __restrict__ g1,
    const float* __restrict__ v2, const float* __restrict__ g2,
    float* __restrict__ ws) {
  int tid = threadIdx.x;
  if (blockIdx.x < 2048) {
    int b = blockIdx.x;
    int chunk = b >> 2, quarter = b & 3;
    int i = chunk & 127;
    const float4* xp = (const float4*)(x + (size_t)chunk * CHUNKF + (size_t)quarter * 8192);
    float acc = 0.f;
#pragma unroll
    for (int it = 0; it < 8; ++it) {
      int f4i = tid + 256 * it;
      float4 v = xp[f4i];
      int t0 = (4 * f4i) & 31;
      acc += v.x * (float)(32 - t0) + v.y * (float)(31 - t0)
           + v.z * (float)(30 - t0) + v.w * (float)(29 - t0);
    }
    for (int off = 32; off >= 1; off >>= 1) acc += __shfl_down(acc, off);
    __shared__ float part[4];
    if ((tid & 63) == 0) part[tid >> 6] = acc;
    __syncthreads();
    if (tid == 0) atomicAdd(&ws[8192 + i], part[0] + part[1] + part[2] + part[3]);
  } else {
    int b = blockIdx.x - 2048;
    bool first = (b < 32);
    int row = first ? b : b - 32;
    int len = first ? 128 : 32;
    const float* v = first ? v1 : v2;
    const float* g = first ? g1 : g2;
    double val = 0.0;
    if (tid < len) { double t = (double)v[row * len + tid]; val = t * t; }
    for (int off = 32; off >= 1; off >>= 1) val += __shfl_down(val, off);
    __shared__ double partial[4];
    if ((tid & 63) == 0) partial[tid >> 6] = val;
    __syncthreads();
    double norm = sqrt(partial[0] + partial[1]);
    if (tid < len) {
      double w = (double)g[row] * (double)v[row * len + tid] / norm;
      double qd = rint(w * 32.0) * 0.03125;
      qd = fmin(fmax(qd, -2.0), 1.984375);
      float qf = (float)qd;
      ushort bf = (ushort)(__float_as_uint(qf) >> 16);
      if (first) {
        ws[row * 128 + tid] = qf;
        ((ushort*)(ws + 8448))[row * 128 + tid] = bf;
      } else {
        ws[4096 + row * 32 + tid] = qf;
        ((ushort*)(ws + 10496))[row * 32 + tid] = bf;
      }
    }
  }
}

__global__ __launch_bounds__(256, 4) void fused_kernel(
    const float* __restrict__ x, const float* __restrict__ ws,
    float* __restrict__ out) {
  const ushort* qw1bf = (const ushort*)(ws + 8448);
  const ushort* qw2bf = (const ushort*)(ws + 10496);

  __shared__ uint xs[8192];
  __shared__ float zred[288];
  __shared__ float kls[128];

  const int tid = threadIdx.x;
  const int wv = tid >> 6;
  const int l  = tid & 63;
  const int g  = l >> 4;
  const int ln = l & 15;

  const int nb  = blockIdx.x >> 8;
  const int hw0 = (blockIdx.x & 255) * 4;
  const float* xblk = x + (size_t)nb * CIN * CHUNKF + (size_t)hw0 * 32;

  float4 xr[8];
#pragma unroll
  for (int k = 0; k < 8; ++k) {
    int f = k * 256 + tid, c = f >> 5, n4 = f & 31;
    xr[k] = *(const float4*)(xblk + (size_t)c * CHUNKF + n4 * 4);
  }

  s16x8 A1[2][4];
#pragma unroll
  for (int jt = 0; jt < 2; ++jt)
#pragma unroll
    for (int ks = 0; ks < 4; ++ks)
      A1[jt][ks] = *(const s16x8*)(qw1bf + (jt * 16 + ln) * 128 + ks * 32 + g * 8);

  {
    int j = tid & 31, grp = tid >> 5;
    const float* qr = ws + j * 128 + grp * 16;
    const float* mr = ws + 8192 + grp * 16;
    float pp = 0.f;
#pragma unroll
    for (int cc = 0; cc < 16; ++cc) pp += qr[cc] * mr[cc];
    zred[j * 8 + grp] = pp;
  }
  __syncthreads();
  if (tid < 32) {
    float t = 0.f;
#pragma unroll
    for (int gg = 0; gg < 8; ++gg) t += zred[tid * 8 + gg];
    zred[256 + tid] = t * (1.0f / 131072.0f);
  }
  __syncthreads();
  if (tid < 128) {
    const float* q2 = ws + 4096 + tid * 32;
    float kk = 0.f;
#pragma unroll 8
    for (int j = 0; j < 32; ++j) kk += q2[j] * zred[256 + j];
    kls[tid] = kk;
  }

  f32x4 acc1[2][2];
#pragma unroll
  for (int a = 0; a < 2; ++a)
#pragma unroll
    for (int b = 0; b < 2; ++b) acc1[a][b] = (f32x4){0.f, 0.f, 0.f, 0.f};

#pragma unroll
  for (int ph = 0; ph < 2; ++ph) {
#pragma unroll
    for (int k = 0; k < 8; ++k) {
      int f = k * 256 + tid, c = f >> 5, n4 = f & 31;
      int u = n4 ^ ((c >> 2) & 6);
      uint4 pk;
      pk.x = pack_hilo(xr[k].x); pk.y = pack_hilo(xr[k].y);
      pk.z = pack_hilo(xr[k].z); pk.w = pack_hilo(xr[k].w);
      *(uint4*)&xs[c * 128 + u * 4] = pk;
    }
    __syncthreads();
    if (ph == 0) {
#pragma unroll
      for (int k = 0; k < 8; ++k) {
        int f = k * 256 + tid, c = f >> 5, n4 = f & 31;
        xr[k] = *(const float4*)(xblk + (size_t)(64 + c) * CHUNKF + n4 * 4);
      }
    }
#pragma unroll
    for (int kl = 0; kl < 2; ++kl) {
#pragma unroll
      for (int nt = 0; nt < 2; ++nt) {
        const int n = wv * 32 + nt * 16 + ln;
        const int base = (kl * 32 + g * 8) * 128;
        const int u = ((n >> 2) ^ (((kl * 32 + g * 8) >> 2) & 6)) * 4 + (n & 3);
        uint q0 = xs[base + 0 * 128 + u], q1 = xs[base + 1 * 128 + u];
        uint q2 = xs[base + 2 * 128 + u], q3 = xs[base + 3 * 128 + u];
        uint q4 = xs[base + 4 * 128 + u], q5 = xs[base + 5 * 128 + u];
        uint q6 = xs[base + 6 * 128 + u], q7 = xs[base + 7 * 128 + u];
        uint4 H, L;
        H.x = (q0 & 0xffffu) | (q1 << 16);  H.y = (q2 & 0xffffu) | (q3 << 16);
        H.z = (q4 & 0xffffu) | (q5 << 16);  H.w = (q6 & 0xffffu) | (q7 << 16);
        L.x = (q0 >> 16) | (q1 & 0xffff0000u); L.y = (q2 >> 16) | (q3 & 0xffff0000u);
        L.z = (q4 >> 16) | (q5 & 0xffff0000u); L.w = (q6 >> 16) | (q7 & 0xffff0000u);
        s16x8 Bh = __builtin_bit_cast(s16x8, H);
        s16x8 Bl = __builtin_bit_cast(s16x8, L);
#pragma unroll
        for (int jt = 0; jt < 2; ++jt) {
          acc1[jt][nt] = __builtin_amdgcn_mfma_f32_16x16x32_bf16(A1[jt][ph * 2 + kl], Bh, acc1[jt][nt], 0, 0, 0);
          acc1[jt][nt] = __builtin_amdgcn_mfma_f32_16x16x32_bf16(A1[jt][ph * 2 + kl], Bl, acc1[jt][nt], 0, 0, 0);
        }
      }
    }
    __syncthreads();
  }

  uint* zw = xs + wv * 1024;
#pragma unroll
  for (int jt = 0; jt < 2; ++jt)
#pragma unroll
    for (int nt = 0; nt < 2; ++nt) {
      int n = nt * 16 + ln;
      int u = (jt * 4 + g) ^ (n & 7);
      uint4 pk;
      pk.x = pack_hilo(acc1[jt][nt][0]);
      pk.y = pack_hilo(acc1[jt][nt][1]);
      pk.z = pack_hilo(acc1[jt][nt][2]);
      pk.w = pack_hilo(acc1[jt][nt][3]);
      *(uint4*)&zw[n * 32 + u * 4] = pk;
    }

  s16x8 Ah[2], Al[2];
#pragma unroll
  for (int mt = 0; mt < 2; ++mt) {
    int n = mt * 16 + ln;
    int u0 = (2 * g) ^ (n & 7);
    int u1 = (2 * g + 1) ^ (n & 7);
    uint4 qa = *(const uint4*)&zw[n * 32 + u0 * 4];
    uint4 qb = *(const uint4*)&zw[n * 32 + u1 * 4];
    uint4 H, L;
    H.x = (qa.x & 0xffffu) | (qa.y << 16);  H.y = (qa.z & 0xffffu) | (qa.w << 16);
    H.z = (qb.x & 0xffffu) | (qb.y << 16);  H.w = (qb.z & 0xffffu) | (qb.w << 16);
    L.x = (qa.x >> 16) | (qa.y & 0xffff0000u); L.y = (qa.z >> 16) | (qa.w & 0xffff0000u);
    L.z = (qb.x >> 16) | (qb.y & 0xffff0000u); L.w = (qb.z >> 16) | (qb.w & 0xffff0000u);
    Ah[mt] = __builtin_bit_cast(s16x8, H);
    Al[mt] = __builtin_bit_cast(s16x8, L);
  }

  const size_t outbase = (size_t)nb * CIN * CHUNKF + (size_t)(hw0 + wv) * 32;
#pragma unroll 1
  for (int h = 0; h < 2; ++h) {
    s16x8 B2[4];
#pragma unroll
    for (int q = 0; q < 4; ++q)
      B2[q] = *(const s16x8*)(qw2bf + ((h * 4 + q) * 16 + ln) * 32 + g * 8);
    f32x4 acc2[4][2];
#pragma unroll
    for (int a = 0; a < 4; ++a)
#pragma unroll
      for (int b = 0; b < 2; ++b) acc2[a][b] = (f32x4){0.f, 0.f, 0.f, 0.f};
#pragma unroll
    for (int mt = 0; mt < 2; ++mt)
#pragma unroll
      for (int q = 0; q < 4; ++q) {
        acc2[q][mt] = __builtin_amdgcn_mfma_f32_16x16x32_bf16(Ah[mt], B2[q], acc2[q][mt], 0, 0, 0);
        acc2[q][mt] = __builtin_amdgcn_mfma_f32_16x16x32_bf16(Al[mt], B2[q], acc2[q][mt], 0, 0, 0);
      }
#pragma unroll
    for (int q = 0; q < 4; ++q) {
      const int nt = h * 4 + q;
      float c0[2], c1[2], c2[2], c3[2], base[2], Qi0 = 0.f;
#pragma unroll
      for (int mt = 0; mt < 2; ++mt) {
        c0[mt] = acc2[q][mt][0];
        c1[mt] = c0[mt] + acc2[q][mt][1];
        c2[mt] = c1[mt] + acc2[q][mt][2];
        c3[mt] = c2[mt] + acc2[q][mt][3];
        float Qi = c3[mt];
        float t1 = __shfl_up(Qi, 16); if (g >= 1) Qi += t1;
        float t2 = __shfl_up(Qi, 32); if (g >= 2) Qi += t2;
        base[mt] = Qi - c3[mt];
        if (mt == 0) Qi0 = Qi;
      }
      float S0tot = __shfl(Qi0, 48 + ln);
      base[1] += S0tot;
      const float kpp = kls[nt * 16 + ln];
      float* op = out + outbase + (size_t)(nt * 16 + ln) * CHUNKF;
#pragma unroll
      for (int mt = 0; mt < 2; ++mt) {
        float Bv = base[mt] - kpp;
        float prev = fminf(fmaxf(Bv, -6.f), 6.f);
        if (mt == 0 && g == 0) prev = 0.f;
        float A0 = fminf(fmaxf(Bv + c0[mt], -6.f), 6.f);
        float A1v = fminf(fmaxf(Bv + c1[mt], -6.f), 6.f);
        float A2v = fminf(fmaxf(Bv + c2[mt], -6.f), 6.f);
        float A3v = fminf(fmaxf(Bv + c3[mt], -6.f), 6.f);
        *(float4*)(op + mt * 16 + g * 4) =
            make_float4(A0 - prev, A1v - A0, A2v - A1v, A3v - A2v);
      }
    }
  }
}

extern "C" void kernel_launch(void* const* d_in, const int* in_sizes, int n_in,
                              void* d_out, int out_size, void* d_ws, size_t ws_size,
                              hipStream_t stream) {
  const float* x  = (const float*)d_in[0];
  const float* v1 = (const float*)d_in[1];
  const float* g1 = (const float*)d_in[2];
  const float* v2 = (const float*)d_in[3];
  const float* g2 = (const float*)d_in[4];
  float* ws  = (float*)d_ws;
  float* out = (float*)d_out;

  // host-side gate: all 1024 blocks must be co-resident (4 blocks/CU) for the
  // deposit/spin pattern; otherwise take the proven two-kernel path.
  int occ = 0;
  hipOccupancyMaxActiveBlocksPerMultiprocessor(&occ, fused_main, 256, 0);

  if (occ >= 4) {
    wnorm_init<<<160, 128, 0, stream>>>(v1, g1, v2, g2, ws);
    fused_main<<<1024, 256, 0, stream>>>(x, ws, out);
  } else {
    hipMemsetAsync(ws + 8192, 0, 128 * sizeof(float), stream);
    wnorm_mean_kernel<<<2208, 256, 0, stream>>>(x, v1, g1, v2, g2, ws);
    fused_kernel<<<1024, 256, 0, stream>>>(x, ws, out);
  }
}